// Round 5
// baseline (194.444 us; speedup 1.0000x reference)
//
#include <hip/hip_runtime.h>
#include <cmath>

// B=32, N=512, IN=128, HID=32, HEADS=4, OUT=128. fp32 in/out; graph int32.
// 5 dispatches: prep_wt ; pack_graph ; gemm_mfma0 ; gat0_gemm ; gat1_head.
// This rev: gat m-loops load H fragments GLOBAL->REGISTER directly (each lane's
// B-fragment is 16B contiguous in plain-layout Ht; 4 quads cover a full 64B
// line, L2-resident) — no LDS staging, no double buffer, no vmcnt asm, no
// in-loop barriers. Compiler software-pipelines the fully-unrolled 8-chunk
// loop. P stays per-lane in registers; e_dst in read-only LDS (one prologue
// sync). Ht stored PLAIN by producers (swizzle no longer needed).

typedef unsigned short ushort_t;
typedef __attribute__((ext_vector_type(8))) short short8;
typedef __attribute__((ext_vector_type(4))) float f32x4;

__device__ __forceinline__ float gelu_f(float v) {
    return 0.5f * v * (1.0f + erff(v * 0.70710678118654752f));
}
__device__ __forceinline__ ushort_t f2bf(float x) {      // round-to-nearest-even
    union { float f; unsigned u; } v; v.f = x;
    return (ushort_t)((v.u + 0x7FFFu + ((v.u >> 16) & 1u)) >> 16);
}
__device__ __forceinline__ ushort_t f2bf_t(float x) {    // truncate (hot softmax path)
    union { float f; unsigned u; } v; v.f = x;
    return (ushort_t)(v.u >> 16);
}

// ---- prep: bf16-transpose lin_W(256x128) me_W0 me_W1 oh_W W0 W1 (128x128) ---
__global__ __launch_bounds__(256) void prep_wt(const float* __restrict__ lin_W,
        const float* __restrict__ me_W0, const float* __restrict__ me_W1,
        const float* __restrict__ oh_W, const float* __restrict__ W0,
        const float* __restrict__ W1, ushort_t* __restrict__ WT) {
    int i = blockIdx.x * 256 + threadIdx.x;          // 114688 total
    if (i < 32768)       { int c = i >> 8, k = i & 255;                   WT[i] = f2bf(lin_W[k * 128 + c]); }
    else if (i < 49152)  { int j = i - 32768;  int c = j >> 7, k = j & 127; WT[i] = f2bf(me_W0[k * 128 + c]); }
    else if (i < 65536)  { int j = i - 49152;  int c = j >> 7, k = j & 127; WT[i] = f2bf(me_W1[k * 128 + c]); }
    else if (i < 81920)  { int j = i - 65536;  int c = j >> 7, k = j & 127; WT[i] = f2bf(oh_W[k * 128 + c]); }
    else if (i < 98304)  { int j = i - 81920;  int c = j >> 7, k = j & 127; WT[i] = f2bf(W0[k * 128 + c]); }
    else if (i < 114688) { int j = i - 98304;  int c = j >> 7, k = j & 127; WT[i] = f2bf(W1[k * 128 + c]); }
}

// ---- pack graph>0 into bitmask: gmask[(b*512+n)*16 + w] bit j = m=w*32+j ----
__global__ __launch_bounds__(256) void pack_graph(const int* __restrict__ g,
                                                  unsigned* __restrict__ gm) {
    int idx = blockIdx.x * 256 + threadIdx.x;        // 262144 = 32*512*16
    const int4* gp = (const int4*)g + (size_t)idx * 8;
    unsigned m = 0;
#pragma unroll
    for (int q = 0; q < 8; q++) {
        int4 v = gp[q];
        m |= (unsigned)(v.x > 0) << (q * 4 + 0);
        m |= (unsigned)(v.y > 0) << (q * 4 + 1);
        m |= (unsigned)(v.z > 0) << (q * 4 + 2);
        m |= (unsigned)(v.w > 0) << (q * 4 + 3);
    }
    gm[idx] = m;
}

// -- 16-row MFMA gemm: Ht bf16 = (X@W)^T (plain layout) ; fused e_src/e_dst ---
__global__ __launch_bounds__(256) void gemm_mfma0(const float* __restrict__ X,
        const ushort_t* __restrict__ WTr, ushort_t* __restrict__ Ht,
        const float* __restrict__ a_s, const float* __restrict__ a_d,
        float* __restrict__ es, float* __restrict__ ed) {
    __shared__ __align__(16) ushort_t abuf[16 * 128];
    __shared__ __align__(16) ushort_t tb[128 * 24];
    __shared__ float2 ered[8 * 16];
    const int tid = threadIdx.x;
    const int row0 = blockIdx.x * 16;
    const int b = row0 >> 9, m0 = row0 & 511;
    const int w = tid >> 6, lane = tid & 63;
    const int quad = lane >> 4, lid = lane & 15;
    {
        int r = tid >> 4, g = tid & 15;
        const float4* src = (const float4*)(X + (row0 + r) * 128 + g * 8);
        float4 a = src[0], bb = src[1];
        short8 p;
        p[0] = (short)f2bf(a.x);  p[1] = (short)f2bf(a.y);
        p[2] = (short)f2bf(a.z);  p[3] = (short)f2bf(a.w);
        p[4] = (short)f2bf(bb.x); p[5] = (short)f2bf(bb.y);
        p[6] = (short)f2bf(bb.z); p[7] = (short)f2bf(bb.w);
        *(short8*)&abuf[r * 128 + ((g ^ (r & 7)) * 8)] = p;
    }
    __syncthreads();
    short8 af[4];
#pragma unroll
    for (int kc = 0; kc < 4; kc++)
        af[kc] = *(const short8*)&abuf[lid * 128 + (((kc * 4 + quad) ^ (lid & 7)) * 8)];
    f32x4 C[2];
#pragma unroll
    for (int i = 0; i < 2; i++) {
        int ct = w + 4 * i;
        const ushort_t* bp = WTr + (ct * 16 + lid) * 128 + quad * 8;
        C[i] = (f32x4){0.f, 0.f, 0.f, 0.f};
#pragma unroll
        for (int kc = 0; kc < 4; kc++) {
            short8 bf = *(const short8*)&bp[kc * 32];
            C[i] = __builtin_amdgcn_mfma_f32_16x16x32_bf16(af[kc], bf, C[i], 0, 0, 0);
        }
    }
#pragma unroll
    for (int i = 0; i < 2; i++) {
        int ct = w + 4 * i, col = ct * 16 + lid;
        float as_c = a_s[col], ad_c = a_d[col];
        float s0[4], d0[4];
#pragma unroll
        for (int r = 0; r < 4; r++) { s0[r] = C[i][r] * as_c; d0[r] = C[i][r] * ad_c; }
#pragma unroll
        for (int st = 1; st <= 8; st <<= 1)
#pragma unroll
            for (int r = 0; r < 4; r++) {
                s0[r] += __shfl_xor(s0[r], st);
                d0[r] += __shfl_xor(d0[r], st);
            }
        if (lid == 0) {
#pragma unroll
            for (int r = 0; r < 4; r++)
                ered[ct * 16 + quad * 4 + r] = make_float2(s0[r], d0[r]);
        }
#pragma unroll
        for (int r = 0; r < 4; r++)
            tb[col * 24 + quad * 4 + r] = f2bf(C[i][r]);
    }
    __syncthreads();
    if (tid < 64) {
        int row = tid & 15, h = tid >> 4;
        float2 pa = ered[(2 * h) * 16 + row], pb = ered[(2 * h + 1) * 16 + row];
        es[(b * 4 + h) * 512 + m0 + row] = pa.x + pb.x;
        ed[(b * 4 + h) * 512 + m0 + row] = pa.y + pb.y;
    }
    {   // plain store: Ht[b][c][m]
        int c = tid >> 1, half = tid & 1;
        *(short8*)&Ht[b * 65536 + c * 512 + m0 + half * 8] = *(const short8*)&tb[c * 24 + half * 8];
    }
}

// ---- K2: gat0 (reg-direct m-loop, no LDS H) -> elu -> gemm vs W1T ----------
__global__ __launch_bounds__(256) void gat0_gemm(const ushort_t* __restrict__ Ht0,
        const float* __restrict__ es0, const float* __restrict__ ed0,
        const unsigned* __restrict__ gmask, const ushort_t* __restrict__ W1T,
        const float* __restrict__ a_s, const float* __restrict__ a_d,
        ushort_t* __restrict__ Ht1, float* __restrict__ es1, float* __restrict__ ed1) {
    __shared__ __align__(16) char smem[11264];
    float*    eds  = (float*)smem;                 // [0,8192) gat phase
    ushort_t* abuf = (ushort_t*)smem;              // gemm phase (over eds), 4KB
    ushort_t* tb   = (ushort_t*)(smem + 4096);     // gemm phase, 6KB
    float2*   ered = (float2*)(smem + 10240);      // gemm phase, 1KB
    const int tid = threadIdx.x;
    const int b = blockIdx.y, n0 = blockIdx.x * 16;
    const int wv = tid >> 6, lane = tid & 63;      // wv = head (gat) / col pair (gemm)
    const int quad = lane >> 4, lid = lane & 15;
    const int n = n0 + lid;                        // this lane's A-row (n-index)
    // H base for this lane's MFMA B-columns (plain layout [c][m])
    const ushort_t* hp0 = Ht0 + b * 65536 + (wv * 32 + lid) * 512;
    const ushort_t* hp1 = hp0 + 16 * 512;
    // per-lane P inputs: e_src scalar + 16 graph-mask words (64B)
    const float es_v = es0[b * 2048 + wv * 512 + n];
    const unsigned* gmrow = gmask + (b * 512 + n) * 16;
    uint4 gq0 = *(const uint4*)(gmrow);
    uint4 gq1 = *(const uint4*)(gmrow + 4);
    uint4 gq2 = *(const uint4*)(gmrow + 8);
    uint4 gq3 = *(const uint4*)(gmrow + 12);
    const unsigned mw[16] = {gq0.x, gq0.y, gq0.z, gq0.w, gq1.x, gq1.y, gq1.z, gq1.w,
                             gq2.x, gq2.y, gq2.z, gq2.w, gq3.x, gq3.y, gq3.z, gq3.w};
    {   // eds: all-heads e_dst (2048 floats) -> LDS, read-only in the loop
        const float4* src = (const float4*)(ed0 + b * 2048);
        float4 v0 = src[tid * 2], v1 = src[tid * 2 + 1];
        ((float4*)eds)[tid * 2] = v0;
        ((float4*)eds)[tid * 2 + 1] = v1;
    }
    __syncthreads();                               // eds visible; loop is sync-free
    const short8 onesf = {0x3F80, 0x3F80, 0x3F80, 0x3F80, 0x3F80, 0x3F80, 0x3F80, 0x3F80};
    f32x4 acc[2], dsf;
    acc[0] = (f32x4){0.f, 0.f, 0.f, 0.f};
    acc[1] = (f32x4){0.f, 0.f, 0.f, 0.f};
    dsf = (f32x4){0.f, 0.f, 0.f, 0.f};
#pragma unroll
    for (int t = 0; t < 8; t++) {
#pragma unroll
        for (int kc = 0; kc < 2; kc++) {
            const int moff = t * 64 + (kc * 4 + quad) * 8;     // 16B H fragment @ m
            short8 b0 = *(const short8*)&hp0[moff];
            short8 b1 = *(const short8*)&hp1[moff];
            // per-lane A-fragment P (head wv, row n, same m range)
            unsigned mb8 = (mw[2 * t + kc] >> (quad * 8)) & 0xffu;
            if ((unsigned)(n - moff) < 8u) mb8 |= 1u << (n - moff);   // self-loop
            float4 e0v = *(const float4*)&eds[wv * 512 + moff];
            float4 e1v = *(const float4*)&eds[wv * 512 + moff + 4];
            float ev[8] = {e0v.x, e0v.y, e0v.z, e0v.w, e1v.x, e1v.y, e1v.z, e1v.w};
            short8 pk;
#pragma unroll
            for (int j = 0; j < 8; j++) {
                float e = es_v + ev[j];
                e = fmaxf(e, 0.2f * e);
                e = ((mb8 >> j) & 1u) ? e : -1e30f;
                pk[j] = (short)f2bf_t(__expf(e));
            }
            acc[0] = __builtin_amdgcn_mfma_f32_16x16x32_bf16(pk, b0, acc[0], 0, 0, 0);
            acc[1] = __builtin_amdgcn_mfma_f32_16x16x32_bf16(pk, b1, acc[1], 0, 0, 0);
            dsf = __builtin_amdgcn_mfma_f32_16x16x32_bf16(pk, onesf, dsf, 0, 0, 0);
        }
    }
    __syncthreads();                                // eds dead; abuf overlay safe
    // ---- m = elu(softmax-agg) -> bf16 A-tile ----
#pragma unroll
    for (int reg = 0; reg < 4; reg++) {
        float inv = 1.0f / dsf[reg];
        int rw = quad * 4 + reg;
#pragma unroll
        for (int ch = 0; ch < 2; ch++) {
            float v = acc[ch][reg] * inv;
            v = v > 0.f ? v : expm1f(v);            // ELU
            int col = wv * 32 + ch * 16 + lid;
            abuf[rw * 128 + (((col >> 3) ^ (rw & 7)) * 8) + (col & 7)] = f2bf(v);
        }
    }
    __syncthreads();
    // ---- gemm vs W1T + fused e1 (1 head) + Ht1 ----
    short8 af[4];
#pragma unroll
    for (int kc = 0; kc < 4; kc++)
        af[kc] = *(const short8*)&abuf[lid * 128 + (((kc * 4 + quad) ^ (lid & 7)) * 8)];
    f32x4 C[2];
#pragma unroll
    for (int i = 0; i < 2; i++) {
        int ct = wv + 4 * i;
        const ushort_t* bp = W1T + (ct * 16 + lid) * 128 + quad * 8;
        C[i] = (f32x4){0.f, 0.f, 0.f, 0.f};
#pragma unroll
        for (int kc = 0; kc < 4; kc++) {
            short8 bf = *(const short8*)&bp[kc * 32];
            C[i] = __builtin_amdgcn_mfma_f32_16x16x32_bf16(af[kc], bf, C[i], 0, 0, 0);
        }
    }
#pragma unroll
    for (int i = 0; i < 2; i++) {
        int ct = wv + 4 * i, col = ct * 16 + lid;
        float as_c = a_s[col], ad_c = a_d[col];
        float s0[4], d0[4];
#pragma unroll
        for (int r = 0; r < 4; r++) { s0[r] = C[i][r] * as_c; d0[r] = C[i][r] * ad_c; }
#pragma unroll
        for (int st = 1; st <= 8; st <<= 1)
#pragma unroll
            for (int r = 0; r < 4; r++) {
                s0[r] += __shfl_xor(s0[r], st);
                d0[r] += __shfl_xor(d0[r], st);
            }
        if (lid == 0) {
#pragma unroll
            for (int r = 0; r < 4; r++)
                ered[ct * 16 + quad * 4 + r] = make_float2(s0[r], d0[r]);
        }
#pragma unroll
        for (int r = 0; r < 4; r++)
            tb[col * 24 + quad * 4 + r] = f2bf(C[i][r]);
    }
    __syncthreads();
    if (tid < 16) {
        float S = 0.f, D = 0.f;
#pragma unroll
        for (int ct = 0; ct < 8; ct++) { float2 p = ered[ct * 16 + tid]; S += p.x; D += p.y; }
        es1[b * 512 + n0 + tid] = S;
        ed1[b * 512 + n0 + tid] = D;
    }
    {   // plain store: Ht1[b][c][m]
        int c = tid >> 1, half = tid & 1;
        *(short8*)&Ht1[b * 65536 + c * 512 + n0 + half * 8] = *(const short8*)&tb[c * 24 + half * 8];
    }
}

// ---- K3: gat1 (reg-direct m-loop) -> ln1 -> linear -> MLP -> ln2 -> head ---
__global__ __launch_bounds__(256) void gat1_head(const ushort_t* __restrict__ Ht,
        const float* __restrict__ es1, const float* __restrict__ ed1,
        const unsigned* __restrict__ gmask, const float* __restrict__ x,
        const float* __restrict__ g1, const float* __restrict__ b1,
        const ushort_t* __restrict__ linT, const float* __restrict__ LB,
        const ushort_t* __restrict__ meT0, const float* __restrict__ B0,
        const ushort_t* __restrict__ meT1, const float* __restrict__ B1,
        const float* __restrict__ g2, const float* __restrict__ b2,
        const ushort_t* __restrict__ ohT, const float* __restrict__ ob,
        const float* __restrict__ g3, const float* __restrict__ b3,
        float* __restrict__ out) {
    __shared__ __align__(16) char smem[25472];
    float*    eds  = (float*)smem;                 // [0,2048) gat phase
    ushort_t* ybuf = (ushort_t*)smem;              // head phase overlays (after loop)
    ushort_t* abuf = (ushort_t*)(smem + 8192);
    ushort_t* tbuf = (ushort_t*)(smem + 12288);
    float*    gbuf = (float*)(smem + 16384);
    float2*   red  = (float2*)(smem + 24832);
    float2*   mvs  = (float2*)(smem + 25344);
    const int tid = threadIdx.x;
    const int b = blockIdx.y, n0 = blockIdx.x * 16;
    const int wv = tid >> 6, lane = tid & 63;
    const int quad = lane >> 4, lid = lane & 15;
    const int n = n0 + lid;                        // this lane's A-row
    const ushort_t* hp0 = Ht + b * 65536 + (wv * 32 + lid) * 512;
    const ushort_t* hp1 = hp0 + 16 * 512;
    const float es_v = es1[b * 512 + n];
    const unsigned* gmrow = gmask + (b * 512 + n) * 16;
    uint4 gq0 = *(const uint4*)(gmrow);
    uint4 gq1 = *(const uint4*)(gmrow + 4);
    uint4 gq2 = *(const uint4*)(gmrow + 8);
    uint4 gq3 = *(const uint4*)(gmrow + 12);
    const unsigned mw[16] = {gq0.x, gq0.y, gq0.z, gq0.w, gq1.x, gq1.y, gq1.z, gq1.w,
                             gq2.x, gq2.y, gq2.z, gq2.w, gq3.x, gq3.y, gq3.z, gq3.w};
    {   // eds: e_dst (512 floats) -> LDS
        float2 edv = ((const float2*)(ed1 + b * 512))[tid];
        ((float2*)eds)[tid] = edv;
    }
    __syncthreads();                               // eds visible; loop is sync-free
    const short8 onesf = {0x3F80, 0x3F80, 0x3F80, 0x3F80, 0x3F80, 0x3F80, 0x3F80, 0x3F80};
    f32x4 acc[2], dsf;
    acc[0] = (f32x4){0.f, 0.f, 0.f, 0.f};
    acc[1] = (f32x4){0.f, 0.f, 0.f, 0.f};
    dsf = (f32x4){0.f, 0.f, 0.f, 0.f};
#pragma unroll
    for (int t = 0; t < 8; t++) {
#pragma unroll
        for (int kc = 0; kc < 2; kc++) {
            const int moff = t * 64 + (kc * 4 + quad) * 8;
            short8 b0 = *(const short8*)&hp0[moff];
            short8 b1 = *(const short8*)&hp1[moff];
            unsigned mb8 = (mw[2 * t + kc] >> (quad * 8)) & 0xffu;
            if ((unsigned)(n - moff) < 8u) mb8 |= 1u << (n - moff);   // self-loop
            float4 e0v = *(const float4*)&eds[moff];
            float4 e1v = *(const float4*)&eds[moff + 4];
            float ev[8] = {e0v.x, e0v.y, e0v.z, e0v.w, e1v.x, e1v.y, e1v.z, e1v.w};
            short8 pk;
#pragma unroll
            for (int j = 0; j < 8; j++) {
                float e = es_v + ev[j];
                e = fmaxf(e, 0.2f * e);
                e = ((mb8 >> j) & 1u) ? e : -1e30f;
                pk[j] = (short)f2bf_t(__expf(e));
            }
            acc[0] = __builtin_amdgcn_mfma_f32_16x16x32_bf16(pk, b0, acc[0], 0, 0, 0);
            acc[1] = __builtin_amdgcn_mfma_f32_16x16x32_bf16(pk, b1, acc[1], 0, 0, 0);
            dsf = __builtin_amdgcn_mfma_f32_16x16x32_bf16(pk, onesf, dsf, 0, 0, 0);
        }
    }
    __syncthreads();                                // eds dead; overlays safe
#pragma unroll
    for (int reg = 0; reg < 4; reg++) {
        float inv = 1.0f / dsf[reg];
        int rw = quad * 4 + reg;
#pragma unroll
        for (int ch = 0; ch < 2; ch++)
            gbuf[rw * 132 + wv * 32 + ch * 16 + lid] = acc[ch][reg] * inv;
    }
    __syncthreads();
    // ---- LN1 over concat(x,G); ybuf bf16 ----
    const int r = tid >> 4, c16 = tid & 15;
    const float4* xp = (const float4*)(x + (b * 512 + n0 + r) * 128);
    float4 vv4[4];
    float s = 0.f, ss = 0.f;
#pragma unroll
    for (int i = 0; i < 4; i++) {
        int c4 = c16 * 4 + i;
        float4 v = (c4 < 32) ? xp[c4] : *(const float4*)&gbuf[r * 132 + (c4 - 32) * 4];
        vv4[i] = v;
        s += v.x + v.y + v.z + v.w;
        ss += v.x * v.x + v.y * v.y + v.z * v.z + v.w * v.w;
    }
#pragma unroll
    for (int st = 1; st <= 8; st <<= 1) { s += __shfl_xor(s, st); ss += __shfl_xor(ss, st); }
    if (c16 == 0) {
        float mu = s * (1.f / 256.f);
        float var = ss * (1.f / 256.f) - mu * mu;
        mvs[r] = make_float2(mu, rsqrtf(var + 1e-5f));
    }
    __syncthreads();
    {
        float mu = mvs[r].x, rstd = mvs[r].y;
#pragma unroll
        for (int half = 0; half < 2; half++) {
            int g = c16 * 2 + half, c0 = g * 8;
            float va[8] = {vv4[half * 2].x, vv4[half * 2].y, vv4[half * 2].z, vv4[half * 2].w,
                           vv4[half * 2 + 1].x, vv4[half * 2 + 1].y, vv4[half * 2 + 1].z, vv4[half * 2 + 1].w};
            short8 p;
#pragma unroll
            for (int e = 0; e < 8; e++)
                p[e] = (short)f2bf((va[e] - mu) * rstd * g1[c0 + e] + b1[c0 + e]);
            *(short8*)&ybuf[r * 256 + ((g ^ (r & 7)) * 8)] = p;
        }
    }
    __syncthreads();
    // ---- GEMM1: M2 = y @ lin_W + lin_b ----
    short8 af8[8];
#pragma unroll
    for (int ks = 0; ks < 8; ks++)
        af8[ks] = *(const short8*)&ybuf[lid * 256 + (((ks * 4 + quad) ^ (lid & 7)) * 8)];
    f32x4 M2[2];
#pragma unroll
    for (int i = 0; i < 2; i++) {
        int ct = wv + 4 * i;
        const ushort_t* bp = linT + (ct * 16 + lid) * 256 + quad * 8;
        M2[i] = (f32x4){0.f, 0.f, 0.f, 0.f};
#pragma unroll
        for (int ks = 0; ks < 8; ks++) {
            short8 bf = *(const short8*)&bp[ks * 32];
            M2[i] = __builtin_amdgcn_mfma_f32_16x16x32_bf16(af8[ks], bf, M2[i], 0, 0, 0);
        }
        float bias = LB[ct * 16 + lid];
#pragma unroll
        for (int reg = 0; reg < 4; reg++) M2[i][reg] += bias;
        int col = ct * 16 + lid, g = col >> 3, pos = col & 7;
#pragma unroll
        for (int reg = 0; reg < 4; reg++) {
            int rw = quad * 4 + reg;
            abuf[rw * 128 + ((g ^ (rw & 7)) * 8) + pos] = f2bf(M2[i][reg]);
        }
    }
    __syncthreads();
    // ---- T = gelu(m2 @ me_W0 + b0) ----
    short8 at[4];
#pragma unroll
    for (int kc = 0; kc < 4; kc++)
        at[kc] = *(const short8*)&abuf[lid * 128 + (((kc * 4 + quad) ^ (lid & 7)) * 8)];
#pragma unroll
    for (int i = 0; i < 2; i++) {
        int ct = wv + 4 * i;
        const ushort_t* bp = meT0 + (ct * 16 + lid) * 128 + quad * 8;
        f32x4 C = (f32x4){0.f, 0.f, 0.f, 0.f};
#pragma unroll
        for (int kc = 0; kc < 4; kc++) {
            short8 bf = *(const short8*)&bp[kc * 32];
            C = __builtin_amdgcn_mfma_f32_16x16x32_bf16(at[kc], bf, C, 0, 0, 0);
        }
        int col = ct * 16 + lid, g = col >> 3, pos = col & 7;
        float bias = B0[col];
#pragma unroll
        for (int reg = 0; reg < 4; reg++) {
            int rw = quad * 4 + reg;
            tbuf[rw * 128 + ((g ^ (rw & 7)) * 8) + pos] = f2bf(gelu_f(C[reg] + bias));
        }
    }
    __syncthreads();
    // ---- enc = T @ me_W1 + b1 ; R = m2 + enc ; ln2 ----
#pragma unroll
    for (int kc = 0; kc < 4; kc++)
        at[kc] = *(const short8*)&tbuf[lid * 128 + (((kc * 4 + quad) ^ (lid & 7)) * 8)];
    f32x4 R[2];
    float sr[4] = {0.f, 0.f, 0.f, 0.f}, ssr[4] = {0.f, 0.f, 0.f, 0.f};
#pragma unroll
    for (int i = 0; i < 2; i++) {
        int ct = wv + 4 * i;
        const ushort_t* bp = meT1 + (ct * 16 + lid) * 128 + quad * 8;
        f32x4 C = (f32x4){0.f, 0.f, 0.f, 0.f};
#pragma unroll
        for (int kc = 0; kc < 4; kc++) {
            short8 bf = *(const short8*)&bp[kc * 32];
            C = __builtin_amdgcn_mfma_f32_16x16x32_bf16(at[kc], bf, C, 0, 0, 0);
        }
        float bias = B1[ct * 16 + lid];
#pragma unroll
        for (int reg = 0; reg < 4; reg++) {
            float v = M2[i][reg] + C[reg] + bias;
            R[i][reg] = v;
            sr[reg] += v; ssr[reg] += v * v;
        }
    }
#pragma unroll
    for (int st = 1; st <= 8; st <<= 1)
#pragma unroll
        for (int reg = 0; reg < 4; reg++) {
            sr[reg] += __shfl_xor(sr[reg], st);
            ssr[reg] += __shfl_xor(ssr[reg], st);
        }
    if (lid == 0) {
#pragma unroll
        for (int reg = 0; reg < 4; reg++)
            red[wv * 16 + quad * 4 + reg] = make_float2(sr[reg], ssr[reg]);
    }
    __syncthreads();
    float mu2[4], rstd2[4];
#pragma unroll
    for (int reg = 0; reg < 4; reg++) {
        float S = 0.f, SS = 0.f;
#pragma unroll
        for (int w4 = 0; w4 < 4; w4++) {
            float2 p = red[w4 * 16 + quad * 4 + reg];
            S += p.x; SS += p.y;
        }
        mu2[reg] = S * (1.f / 128.f);
        float var = SS * (1.f / 128.f) - mu2[reg] * mu2[reg];
        rstd2[reg] = rsqrtf(var + 1e-5f);
    }
#pragma unroll
    for (int i = 0; i < 2; i++) {
        int col = (wv + 4 * i) * 16 + lid, g = col >> 3, pos = col & 7;
        float gv = g2[col], bv = b2[col];
#pragma unroll
        for (int reg = 0; reg < 4; reg++) {
            int rw = quad * 4 + reg;
            float v = (R[i][reg] - mu2[reg]) * rstd2[reg] * gv + bv;
            tbuf[rw * 128 + ((g ^ (rw & 7)) * 8) + pos] = f2bf(v);
        }
    }
    __syncthreads();
    // ---- V = gelu(r @ oh_W + ob) ; ln3 ; store ----
#pragma unroll
    for (int kc = 0; kc < 4; kc++)
        at[kc] = *(const short8*)&tbuf[lid * 128 + (((kc * 4 + quad) ^ (lid & 7)) * 8)];
    f32x4 V[2];
#pragma unroll
    for (int reg = 0; reg < 4; reg++) { sr[reg] = 0.f; ssr[reg] = 0.f; }
#pragma unroll
    for (int i = 0; i < 2; i++) {
        int ct = wv + 4 * i;
        const ushort_t* bp = ohT + (ct * 16 + lid) * 128 + quad * 8;
        f32x4 C = (f32x4){0.f, 0.f, 0.f, 0.f};
#pragma unroll
        for (int kc = 0; kc < 4; kc++) {
            short8 bf = *(const short8*)&bp[kc * 32];
            C = __builtin_amdgcn_mfma_f32_16x16x32_bf16(at[kc], bf, C, 0, 0, 0);
        }
        float bias = ob[ct * 16 + lid];
#pragma unroll
        for (int reg = 0; reg < 4; reg++) {
            float v = gelu_f(C[reg] + bias);
            V[i][reg] = v;
            sr[reg] += v; ssr[reg] += v * v;
        }
    }
#pragma unroll
    for (int st = 1; st <= 8; st <<= 1)
#pragma unroll
        for (int reg = 0; reg < 4; reg++) {
            sr[reg] += __shfl_xor(sr[reg], st);
            ssr[reg] += __shfl_xor(ssr[reg], st);
        }
    if (lid == 0) {
#pragma unroll
        for (int reg = 0; reg < 4; reg++)
            red[wv * 16 + quad * 4 + reg] = make_float2(sr[reg], ssr[reg]);
    }
    __syncthreads();
#pragma unroll
    for (int reg = 0; reg < 4; reg++) {
        float S = 0.f, SS = 0.f;
#pragma unroll
        for (int w4 = 0; w4 < 4; w4++) {
            float2 p = red[w4 * 16 + quad * 4 + reg];
            S += p.x; SS += p.y;
        }
        mu2[reg] = S * (1.f / 128.f);
        float var = SS * (1.f / 128.f) - mu2[reg] * mu2[reg];
        rstd2[reg] = rsqrtf(var + 1e-5f);
    }
#pragma unroll
    for (int i = 0; i < 2; i++) {
        int col = (wv + 4 * i) * 16 + lid;
        float gv = g3[col], bv = b3[col];
#pragma unroll
        for (int reg = 0; reg < 4; reg++)
            out[(b * 512 + n0 + quad * 4 + reg) * 128 + col] =
                (V[i][reg] - mu2[reg]) * rstd2[reg] * gv + bv;
    }
}

extern "C" void kernel_launch(void* const* d_in, const int* in_sizes, int n_in,
                              void* d_out, int out_size, void* d_ws, size_t ws_size,
                              hipStream_t stream) {
    const float* x      = (const float*)d_in[0];
    const int*   graph  = (const int*)d_in[1];
    const float* a_src0 = (const float*)d_in[3];
    const float* a_dst0 = (const float*)d_in[4];
    const float* a_src1 = (const float*)d_in[6];
    const float* a_dst1 = (const float*)d_in[7];
    float* out = (float*)d_out;

    float* ws  = (float*)d_ws;
    ushort_t* Ht0  = (ushort_t*)ws;               // 2097152 bf16
    ushort_t* Ht1  = Ht0 + 2097152;               // 2097152 bf16
    float*    e0s  = ws + 2097152;                // 65536
    float*    e0d  = e0s + 65536;                 // 65536
    float*    e1s  = e0d + 65536;                 // 16384
    float*    e1d  = e1s + 16384;                 // 16384
    ushort_t* WT   = (ushort_t*)(e1d + 16384);    // 114688 bf16
    ushort_t* linT = WT;                          // 32768
    ushort_t* meT0 = WT + 32768;                  // 16384
    ushort_t* meT1 = WT + 49152;                  // 16384
    ushort_t* ohT  = WT + 65536;                  // 16384
    ushort_t* W0T  = WT + 81920;                  // 16384
    ushort_t* W1T  = WT + 98304;                  // 16384
    unsigned* gmask = (unsigned*)(WT + 114688);   // 262144 uint32 = 1 MB

    prep_wt<<<448, 256, 0, stream>>>((const float*)d_in[10], (const float*)d_in[12],
                                     (const float*)d_in[14], (const float*)d_in[18],
                                     (const float*)d_in[2], (const float*)d_in[5], WT);
    pack_graph<<<1024, 256, 0, stream>>>(graph, gmask);
    gemm_mfma0<<<1024, 256, 0, stream>>>(x, W0T, Ht0, a_src0, a_dst0, e0s, e0d);
    gat0_gemm<<<dim3(32, 32), 256, 0, stream>>>(Ht0, e0s, e0d, gmask, W1T,
                                                a_src1, a_dst1, Ht1, e1s, e1d);
    gat1_head<<<dim3(32, 32), 256, 0, stream>>>(Ht1, e1s, e1d, gmask, x,
                                                (const float*)d_in[8], (const float*)d_in[9],
                                                linT, (const float*)d_in[11],
                                                meT0, (const float*)d_in[13],
                                                meT1, (const float*)d_in[15],
                                                (const float*)d_in[16], (const float*)d_in[17],
                                                ohT, (const float*)d_in[19],
                                                (const float*)d_in[20], (const float*)d_in[21],
                                                out);
}

// Round 6
// 182.078 us; speedup vs baseline: 1.0679x; 1.0679x over previous
//
#include <hip/hip_runtime.h>
#include <cmath>

// B=32, N=512, IN=128, HID=32, HEADS=4, OUT=128. fp32 in/out; graph int32.
// 4 dispatches: prep_pack ; gemm_mfma0 ; gat0_gemm ; gat1_head.
// gat0: BARRIER-FREE m-loop (per-lane P in registers — head-indexed so no
//   duplicated exp work), per-wave double-buffered linear global_load_lds of
//   pre-swizzled Ht, counted s_waitcnt vmcnt(4).
// gat1: shared-ps pipelined m-loop (1 head -> per-lane P would duplicate 4x;
//   measured +4us regression twice). ps is DOUBLE-BUFFERED so only ONE
//   s_barrier per chunk is needed (WAR on ps[t&1] has barrier t+1 between
//   read@t and write@t+2; hsb is wave-private so vmcnt suffices for it).

typedef unsigned short ushort_t;
typedef __attribute__((ext_vector_type(8))) short short8;
typedef __attribute__((ext_vector_type(4))) short s16x4;
typedef __attribute__((ext_vector_type(4))) float f32x4;

__device__ __forceinline__ float gelu_f(float v) {
    return 0.5f * v * (1.0f + erff(v * 0.70710678118654752f));
}
__device__ __forceinline__ ushort_t f2bf(float x) {      // round-to-nearest-even
    union { float f; unsigned u; } v; v.f = x;
    return (ushort_t)((v.u + 0x7FFFu + ((v.u >> 16) & 1u)) >> 16);
}
__device__ __forceinline__ ushort_t f2bf_t(float x) {    // truncate (hot softmax path)
    union { float f; unsigned u; } v; v.f = x;
    return (ushort_t)(v.u >> 16);
}

// async 16B/lane global->LDS (LDS dest = wave-uniform base + lane*16)
__device__ __forceinline__ void gload_lds16(const ushort_t* g, ushort_t* l) {
    __builtin_amdgcn_global_load_lds((__attribute__((address_space(1))) void*)g,
                                     (__attribute__((address_space(3))) void*)l, 16, 0, 0);
}
// stage one 64-col chunk of pre-swizzled Ht: wave wv covers rows wv*32..+31.
__device__ __forceinline__ void stage_chunk(const ushort_t* src, ushort_t* dst,
                                            int wv, int lane) {
#pragma unroll
    for (int i = 0; i < 4; i++) {
        int rbase = wv * 32 + i * 8;
        gload_lds16(src + (rbase + (lane >> 3)) * 512 + (lane & 7) * 8,
                    dst + rbase * 64);
    }
}

// ---- merged: bf16-transpose of 6 weight mats + graph>0 bitmask pack --------
__global__ __launch_bounds__(256) void prep_pack(const float* __restrict__ lin_W,
        const float* __restrict__ me_W0, const float* __restrict__ me_W1,
        const float* __restrict__ oh_W, const float* __restrict__ W0,
        const float* __restrict__ W1, ushort_t* __restrict__ WT,
        const int* __restrict__ g, unsigned* __restrict__ gm) {
    if (blockIdx.x < 448) {
        int i = blockIdx.x * 256 + threadIdx.x;          // 114688 total
        if (i < 32768)       { int c = i >> 8, k = i & 255;                   WT[i] = f2bf(lin_W[k * 128 + c]); }
        else if (i < 49152)  { int j = i - 32768;  int c = j >> 7, k = j & 127; WT[i] = f2bf(me_W0[k * 128 + c]); }
        else if (i < 65536)  { int j = i - 49152;  int c = j >> 7, k = j & 127; WT[i] = f2bf(me_W1[k * 128 + c]); }
        else if (i < 81920)  { int j = i - 65536;  int c = j >> 7, k = j & 127; WT[i] = f2bf(oh_W[k * 128 + c]); }
        else if (i < 98304)  { int j = i - 81920;  int c = j >> 7, k = j & 127; WT[i] = f2bf(W0[k * 128 + c]); }
        else if (i < 114688) { int j = i - 98304;  int c = j >> 7, k = j & 127; WT[i] = f2bf(W1[k * 128 + c]); }
    } else {
        int idx = (blockIdx.x - 448) * 256 + threadIdx.x;  // 262144 = 32*512*16
        const int4* gp = (const int4*)g + (size_t)idx * 8;
        unsigned m = 0;
#pragma unroll
        for (int q = 0; q < 8; q++) {
            int4 v = gp[q];
            m |= (unsigned)(v.x > 0) << (q * 4 + 0);
            m |= (unsigned)(v.y > 0) << (q * 4 + 1);
            m |= (unsigned)(v.z > 0) << (q * 4 + 2);
            m |= (unsigned)(v.w > 0) << (q * 4 + 3);
        }
        gm[idx] = m;
    }
}

// -- 16-row MFMA gemm: Ht bf16 = (X@W)^T (PRE-SWIZZLED) ; fused e_src/e_dst ---
__global__ __launch_bounds__(256) void gemm_mfma0(const float* __restrict__ X,
        const ushort_t* __restrict__ WTr, ushort_t* __restrict__ Ht,
        const float* __restrict__ a_s, const float* __restrict__ a_d,
        float* __restrict__ es, float* __restrict__ ed) {
    __shared__ __align__(16) ushort_t abuf[16 * 128];
    __shared__ __align__(16) ushort_t tb[128 * 24];
    __shared__ float2 ered[8 * 16];
    const int tid = threadIdx.x;
    const int row0 = blockIdx.x * 16;
    const int b = row0 >> 9, m0 = row0 & 511;
    const int w = tid >> 6, lane = tid & 63;
    const int quad = lane >> 4, lid = lane & 15;
    {
        int r = tid >> 4, g = tid & 15;
        const float4* src = (const float4*)(X + (row0 + r) * 128 + g * 8);
        float4 a = src[0], bb = src[1];
        short8 p;
        p[0] = (short)f2bf(a.x);  p[1] = (short)f2bf(a.y);
        p[2] = (short)f2bf(a.z);  p[3] = (short)f2bf(a.w);
        p[4] = (short)f2bf(bb.x); p[5] = (short)f2bf(bb.y);
        p[6] = (short)f2bf(bb.z); p[7] = (short)f2bf(bb.w);
        *(short8*)&abuf[r * 128 + ((g ^ (r & 7)) * 8)] = p;
    }
    __syncthreads();
    short8 af[4];
#pragma unroll
    for (int kc = 0; kc < 4; kc++)
        af[kc] = *(const short8*)&abuf[lid * 128 + (((kc * 4 + quad) ^ (lid & 7)) * 8)];
    f32x4 C[2];
#pragma unroll
    for (int i = 0; i < 2; i++) {
        int ct = w + 4 * i;
        const ushort_t* bp = WTr + (ct * 16 + lid) * 128 + quad * 8;
        C[i] = (f32x4){0.f, 0.f, 0.f, 0.f};
#pragma unroll
        for (int kc = 0; kc < 4; kc++) {
            short8 bf = *(const short8*)&bp[kc * 32];
            C[i] = __builtin_amdgcn_mfma_f32_16x16x32_bf16(af[kc], bf, C[i], 0, 0, 0);
        }
    }
#pragma unroll
    for (int i = 0; i < 2; i++) {
        int ct = w + 4 * i, col = ct * 16 + lid;
        float as_c = a_s[col], ad_c = a_d[col];
        float s0[4], d0[4];
#pragma unroll
        for (int r = 0; r < 4; r++) { s0[r] = C[i][r] * as_c; d0[r] = C[i][r] * ad_c; }
#pragma unroll
        for (int st = 1; st <= 8; st <<= 1)
#pragma unroll
            for (int r = 0; r < 4; r++) {
                s0[r] += __shfl_xor(s0[r], st);
                d0[r] += __shfl_xor(d0[r], st);
            }
        if (lid == 0) {
#pragma unroll
            for (int r = 0; r < 4; r++)
                ered[ct * 16 + quad * 4 + r] = make_float2(s0[r], d0[r]);
        }
#pragma unroll
        for (int r = 0; r < 4; r++)
            tb[col * 24 + quad * 4 + r] = f2bf(C[i][r]);
    }
    __syncthreads();
    if (tid < 64) {
        int row = tid & 15, h = tid >> 4;
        float2 pa = ered[(2 * h) * 16 + row], pb = ered[(2 * h + 1) * 16 + row];
        es[(b * 4 + h) * 512 + m0 + row] = pa.x + pb.x;
        ed[(b * 4 + h) * 512 + m0 + row] = pa.y + pb.y;
    }
    {   // pre-swizzled store: group g of m-chunk XORed with (c&7)
        int c = tid >> 1, half = tid & 1;
        int m = m0 + half * 8;
        int msw = (m & ~63) | ((((m >> 3) ^ c) & 7) << 3);
        *(short8*)&Ht[b * 65536 + c * 512 + msw] = *(const short8*)&tb[c * 24 + half * 8];
    }
}

// ---- K2: gat0 (barrier-free m-loop) -> elu -> gemm vs W1T -> Ht1, e1 -------
__global__ __launch_bounds__(256) void gat0_gemm(const ushort_t* __restrict__ Ht0,
        const float* __restrict__ es0, const float* __restrict__ ed0,
        const unsigned* __restrict__ gmask, const ushort_t* __restrict__ W1T,
        const float* __restrict__ a_s, const float* __restrict__ a_d,
        ushort_t* __restrict__ Ht1, float* __restrict__ es1, float* __restrict__ ed1) {
    __shared__ __align__(16) char smem[40960];
    ushort_t* hsb0 = (ushort_t*)smem;              // [0,16384) dbuf A
    ushort_t* hsb1 = (ushort_t*)(smem + 16384);    // [16384,32768) dbuf B
    float*    eds  = (float*)(smem + 32768);       // [32768,40960) e_dst 4 heads
    ushort_t* abuf = (ushort_t*)(smem + 32768);    // gemm phase (over eds), 4KB
    ushort_t* tb   = (ushort_t*)smem;              // gemm phase, 6KB
    float2*   ered = (float2*)(smem + 6144);       // gemm phase, 1KB
    const int tid = threadIdx.x;
    const int b = blockIdx.y, n0 = blockIdx.x * 16;
    const int wv = tid >> 6, lane = tid & 63;      // wv = head (gat) / col pair (gemm)
    const int quad = lane >> 4, lid = lane & 15;
    const int n = n0 + lid;                        // this lane's A-row (n-index)
    const ushort_t* hsrc = Ht0 + b * 65536;
    // per-lane P inputs: e_src scalar + 16 graph-mask words (64B)
    const float es_v = es0[b * 2048 + wv * 512 + n];
    const unsigned* gmrow = gmask + (b * 512 + n) * 16;
    uint4 gq0 = *(const uint4*)(gmrow);
    uint4 gq1 = *(const uint4*)(gmrow + 4);
    uint4 gq2 = *(const uint4*)(gmrow + 8);
    uint4 gq3 = *(const uint4*)(gmrow + 12);
    const unsigned mw[16] = {gq0.x, gq0.y, gq0.z, gq0.w, gq1.x, gq1.y, gq1.z, gq1.w,
                             gq2.x, gq2.y, gq2.z, gq2.w, gq3.x, gq3.y, gq3.z, gq3.w};
    {   // eds: all-heads e_dst (2048 floats) -> LDS, read-only in the loop
        const float4* src = (const float4*)(ed0 + b * 2048);
        float4 v0 = src[tid * 2], v1 = src[tid * 2 + 1];
        ((float4*)eds)[tid * 2] = v0;
        ((float4*)eds)[tid * 2 + 1] = v1;
    }
    __builtin_amdgcn_sched_barrier(0);
    stage_chunk(hsrc, hsb0, wv, lane);             // prologue: chunk 0 in flight
    __builtin_amdgcn_sched_barrier(0);
    asm volatile("s_waitcnt lgkmcnt(0)" ::: "memory");
    __builtin_amdgcn_s_barrier();                  // eds visible; chunk0 still in flight
    __builtin_amdgcn_sched_barrier(0);
    const short8 onesf = {0x3F80, 0x3F80, 0x3F80, 0x3F80, 0x3F80, 0x3F80, 0x3F80, 0x3F80};
    f32x4 acc[2], dsf;
    acc[0] = (f32x4){0.f, 0.f, 0.f, 0.f};
    acc[1] = (f32x4){0.f, 0.f, 0.f, 0.f};
    dsf = (f32x4){0.f, 0.f, 0.f, 0.f};
#pragma unroll
    for (int t = 0; t < 8; t++) {
        ushort_t* cbuf = (t & 1) ? hsb1 : hsb0;
        // ---- per-lane A-fragment P (head wv, row n, m = t*64+kc*32+quad*8) ----
        short8 af[2];
#pragma unroll
        for (int kc = 0; kc < 2; kc++) {
            const int base = t * 64 + kc * 32 + quad * 8;
            unsigned mb8 = (mw[2 * t + kc] >> (quad * 8)) & 0xffu;
            if ((unsigned)(n - base) < 8u) mb8 |= 1u << (n - base);   // self-loop
            float4 e0v = *(const float4*)&eds[wv * 512 + base];
            float4 e1v = *(const float4*)&eds[wv * 512 + base + 4];
            float ev[8] = {e0v.x, e0v.y, e0v.z, e0v.w, e1v.x, e1v.y, e1v.z, e1v.w};
            short8 pk;
#pragma unroll
            for (int j = 0; j < 8; j++) {
                float e = es_v + ev[j];
                e = fmaxf(e, 0.2f * e);
                e = ((mb8 >> j) & 1u) ? e : -1e30f;
                pk[j] = (short)f2bf_t(__expf(e));
            }
            af[kc] = pk;
        }
        if (t < 7) stage_chunk(hsrc + (t + 1) * 64, (t & 1) ? hsb0 : hsb1, wv, lane);
        __builtin_amdgcn_sched_barrier(0);          // pin stage above the wait
        if (t < 7) asm volatile("s_waitcnt vmcnt(4)" ::: "memory");   // own chunk t done
        else       asm volatile("s_waitcnt vmcnt(0)" ::: "memory");
        __builtin_amdgcn_sched_barrier(0);          // pin ds_reads below the wait
#pragma unroll
        for (int kc = 0; kc < 2; kc++) {
            const int gsw = ((kc * 4 + quad) ^ (lid & 7)) * 8;
            short8 b0 = *(const short8*)&cbuf[(wv * 32 + lid) * 64 + gsw];
            short8 b1 = *(const short8*)&cbuf[(wv * 32 + 16 + lid) * 64 + gsw];
            acc[0] = __builtin_amdgcn_mfma_f32_16x16x32_bf16(af[kc], b0, acc[0], 0, 0, 0);
            acc[1] = __builtin_amdgcn_mfma_f32_16x16x32_bf16(af[kc], b1, acc[1], 0, 0, 0);
            dsf = __builtin_amdgcn_mfma_f32_16x16x32_bf16(af[kc], onesf, dsf, 0, 0, 0);
        }
    }
    __syncthreads();                                // gat LDS dead; overlays safe
    // ---- m = elu(softmax-agg) -> bf16 A-tile ----
#pragma unroll
    for (int reg = 0; reg < 4; reg++) {
        float inv = 1.0f / dsf[reg];
        int rw = quad * 4 + reg;
#pragma unroll
        for (int ch = 0; ch < 2; ch++) {
            float v = acc[ch][reg] * inv;
            v = v > 0.f ? v : expm1f(v);            // ELU
            int col = wv * 32 + ch * 16 + lid;
            abuf[rw * 128 + (((col >> 3) ^ (rw & 7)) * 8) + (col & 7)] = f2bf(v);
        }
    }
    __syncthreads();
    // ---- gemm vs W1T + fused e1 (1 head) + Ht1 ----
    short8 af[4];
#pragma unroll
    for (int kc = 0; kc < 4; kc++)
        af[kc] = *(const short8*)&abuf[lid * 128 + (((kc * 4 + quad) ^ (lid & 7)) * 8)];
    f32x4 C[2];
#pragma unroll
    for (int i = 0; i < 2; i++) {
        int ct = wv + 4 * i;
        const ushort_t* bp = W1T + (ct * 16 + lid) * 128 + quad * 8;
        C[i] = (f32x4){0.f, 0.f, 0.f, 0.f};
#pragma unroll
        for (int kc = 0; kc < 4; kc++) {
            short8 bf = *(const short8*)&bp[kc * 32];
            C[i] = __builtin_amdgcn_mfma_f32_16x16x32_bf16(af[kc], bf, C[i], 0, 0, 0);
        }
    }
#pragma unroll
    for (int i = 0; i < 2; i++) {
        int ct = wv + 4 * i, col = ct * 16 + lid;
        float as_c = a_s[col], ad_c = a_d[col];
        float s0[4], d0[4];
#pragma unroll
        for (int r = 0; r < 4; r++) { s0[r] = C[i][r] * as_c; d0[r] = C[i][r] * ad_c; }
#pragma unroll
        for (int st = 1; st <= 8; st <<= 1)
#pragma unroll
            for (int r = 0; r < 4; r++) {
                s0[r] += __shfl_xor(s0[r], st);
                d0[r] += __shfl_xor(d0[r], st);
            }
        if (lid == 0) {
#pragma unroll
            for (int r = 0; r < 4; r++)
                ered[ct * 16 + quad * 4 + r] = make_float2(s0[r], d0[r]);
        }
#pragma unroll
        for (int r = 0; r < 4; r++)
            tb[col * 24 + quad * 4 + r] = f2bf(C[i][r]);
    }
    __syncthreads();
    if (tid < 16) {
        float S = 0.f, D = 0.f;
#pragma unroll
        for (int ct = 0; ct < 8; ct++) { float2 p = ered[ct * 16 + tid]; S += p.x; D += p.y; }
        es1[b * 512 + n0 + tid] = S;
        ed1[b * 512 + n0 + tid] = D;
    }
    {   // pre-swizzled store for gat1's linear global_load_lds staging
        int c = tid >> 1, half = tid & 1;
        int m = n0 + half * 8;
        int msw = (m & ~63) | ((((m >> 3) ^ c) & 7) << 3);
        *(short8*)&Ht1[b * 65536 + c * 512 + msw] = *(const short8*)&tb[c * 24 + half * 8];
    }
}

// ---- K3: gat1 (shared-ps, ONE barrier/chunk) -> ln1 -> linear -> MLP -> ... -
__global__ __launch_bounds__(256) void gat1_head(const ushort_t* __restrict__ Ht,
        const float* __restrict__ es1, const float* __restrict__ ed1,
        const unsigned* __restrict__ gmask, const float* __restrict__ x,
        const float* __restrict__ g1, const float* __restrict__ b1,
        const ushort_t* __restrict__ linT, const float* __restrict__ LB,
        const ushort_t* __restrict__ meT0, const float* __restrict__ B0,
        const ushort_t* __restrict__ meT1, const float* __restrict__ B1,
        const float* __restrict__ g2, const float* __restrict__ b2,
        const ushort_t* __restrict__ ohT, const float* __restrict__ ob,
        const float* __restrict__ g3, const float* __restrict__ b3,
        float* __restrict__ out) {
    __shared__ __align__(16) char smem[38912];
    ushort_t* hsb0 = (ushort_t*)smem;              // [0,16384) dbuf A
    ushort_t* hsb1 = (ushort_t*)(smem + 16384);    // [16384,32768) dbuf B
    ushort_t* ps0  = (ushort_t*)(smem + 32768);    // [32768,34816) P dbuf A
    ushort_t* ps1  = (ushort_t*)(smem + 34816);    // [34816,36864) P dbuf B
    float*    eds  = (float*)(smem + 36864);       // [36864,38912) e_dst row
    ushort_t* ybuf = (ushort_t*)smem;              // head phase overlays
    ushort_t* abuf = (ushort_t*)(smem + 8192);
    ushort_t* tbuf = (ushort_t*)(smem + 12288);
    float*    gbuf = (float*)(smem + 16384);
    float2*   red  = (float2*)(smem + 24832);
    float2*   mvs  = (float2*)(smem + 25344);
    const int tid = threadIdx.x;
    const int b = blockIdx.y, n0 = blockIdx.x * 16;
    const int wv = tid >> 6, lane = tid & 63;
    const int quad = lane >> 4, lid = lane & 15;
    const int pn = tid >> 4, q = tid & 15, off = q * 4;   // P: 256 thr x 4 m
    const int ng = n0 + pn;
    const ushort_t* hsrc = Ht + b * 65536;
    const float es_v = es1[b * 512 + ng];
    const unsigned* gmrow = gmask + (b * 512 + ng) * 16;
    unsigned mword[8];
#pragma unroll
    for (int t = 0; t < 8; t++) mword[t] = gmrow[2 * t + (q >> 3)];
    float2 edv = ((const float2*)(ed1 + b * 512))[tid];
    stage_chunk(hsrc, hsb0, wv, lane);             // prologue: chunk 0 in flight
    ((float2*)eds)[tid] = edv;
    asm volatile("s_waitcnt lgkmcnt(0)" ::: "memory");
    __builtin_amdgcn_s_barrier();                  // eds visible; chunk0 still in flight
    __builtin_amdgcn_sched_barrier(0);
    const short8 onesf = {0x3F80, 0x3F80, 0x3F80, 0x3F80, 0x3F80, 0x3F80, 0x3F80, 0x3F80};
    f32x4 acc[2], dsf;
    acc[0] = (f32x4){0.f, 0.f, 0.f, 0.f};
    acc[1] = (f32x4){0.f, 0.f, 0.f, 0.f};
    dsf = (f32x4){0.f, 0.f, 0.f, 0.f};
#pragma unroll
    for (int t = 0; t < 8; t++) {
        const int mc = t * 64;
        ushort_t* cbuf = (t & 1) ? hsb1 : hsb0;
        ushort_t* pbuf = (t & 1) ? ps1 : ps0;
        const int mbase = mc + off;
        float4 ev4 = *(const float4*)&eds[mbase];
        if (t < 7) stage_chunk(hsrc + mc + 64, (t & 1) ? hsb0 : hsb1, wv, lane);
        unsigned mb4 = (mword[t] >> ((q & 7) * 4)) & 0xFu;
        if ((unsigned)(ng - mbase) < 4u) mb4 |= 1u << (ng - mbase);   // self-loop
        float ev[4] = {ev4.x, ev4.y, ev4.z, ev4.w};
        s16x4 pk;
#pragma unroll
        for (int j = 0; j < 4; j++) {
            float e = es_v + ev[j];
            e = fmaxf(e, 0.2f * e);
            e = ((mb4 >> j) & 1u) ? e : -1e30f;
            pk[j] = (short)f2bf_t(__expf(e));
        }
        *(s16x4*)&pbuf[pn * 64 + (((off >> 3) ^ (pn & 7)) * 8) + (off & 7)] = pk;
        if (t < 7) asm volatile("s_waitcnt vmcnt(4)" ::: "memory");
        else       asm volatile("s_waitcnt vmcnt(0)" ::: "memory");
        asm volatile("s_waitcnt lgkmcnt(0)" ::: "memory");
        __builtin_amdgcn_s_barrier();               // single barrier per chunk
        __builtin_amdgcn_sched_barrier(0);          // pin LDS reads below the waits
#pragma unroll
        for (int kc = 0; kc < 2; kc++) {
            const int gsw = ((kc * 4 + quad) ^ (lid & 7)) * 8;
            short8 a = *(const short8*)&pbuf[lid * 64 + gsw];
            short8 b0 = *(const short8*)&cbuf[(wv * 32 + lid) * 64 + gsw];
            short8 b1 = *(const short8*)&cbuf[(wv * 32 + 16 + lid) * 64 + gsw];
            acc[0] = __builtin_amdgcn_mfma_f32_16x16x32_bf16(a, b0, acc[0], 0, 0, 0);
            acc[1] = __builtin_amdgcn_mfma_f32_16x16x32_bf16(a, b1, acc[1], 0, 0, 0);
            dsf = __builtin_amdgcn_mfma_f32_16x16x32_bf16(a, onesf, dsf, 0, 0, 0);
        }
    }
    __syncthreads();                                // gat LDS dead; overlays safe
#pragma unroll
    for (int reg = 0; reg < 4; reg++) {
        float inv = 1.0f / dsf[reg];
        int rw = quad * 4 + reg;
#pragma unroll
        for (int ch = 0; ch < 2; ch++)
            gbuf[rw * 132 + wv * 32 + ch * 16 + lid] = acc[ch][reg] * inv;
    }
    __syncthreads();
    // ---- LN1 over concat(x,G); ybuf bf16 ----
    const int r = tid >> 4, c16 = tid & 15;
    const float4* xp = (const float4*)(x + (b * 512 + n0 + r) * 128);
    float4 vv4[4];
    float s = 0.f, ss = 0.f;
#pragma unroll
    for (int i = 0; i < 4; i++) {
        int c4 = c16 * 4 + i;
        float4 v = (c4 < 32) ? xp[c4] : *(const float4*)&gbuf[r * 132 + (c4 - 32) * 4];
        vv4[i] = v;
        s += v.x + v.y + v.z + v.w;
        ss += v.x * v.x + v.y * v.y + v.z * v.z + v.w * v.w;
    }
#pragma unroll
    for (int st = 1; st <= 8; st <<= 1) { s += __shfl_xor(s, st); ss += __shfl_xor(ss, st); }
    if (c16 == 0) {
        float mu = s * (1.f / 256.f);
        float var = ss * (1.f / 256.f) - mu * mu;
        mvs[r] = make_float2(mu, rsqrtf(var + 1e-5f));
    }
    __syncthreads();
    {
        float mu = mvs[r].x, rstd = mvs[r].y;
#pragma unroll
        for (int half = 0; half < 2; half++) {
            int g = c16 * 2 + half, c0 = g * 8;
            float va[8] = {vv4[half * 2].x, vv4[half * 2].y, vv4[half * 2].z, vv4[half * 2].w,
                           vv4[half * 2 + 1].x, vv4[half * 2 + 1].y, vv4[half * 2 + 1].z, vv4[half * 2 + 1].w};
            short8 p;
#pragma unroll
            for (int e = 0; e < 8; e++)
                p[e] = (short)f2bf((va[e] - mu) * rstd * g1[c0 + e] + b1[c0 + e]);
            *(short8*)&ybuf[r * 256 + ((g ^ (r & 7)) * 8)] = p;
        }
    }
    __syncthreads();
    // ---- GEMM1: M2 = y @ lin_W + lin_b ----
    short8 af8[8];
#pragma unroll
    for (int ks = 0; ks < 8; ks++)
        af8[ks] = *(const short8*)&ybuf[lid * 256 + (((ks * 4 + quad) ^ (lid & 7)) * 8)];
    f32x4 M2[2];
#pragma unroll
    for (int i = 0; i < 2; i++) {
        int ct = wv + 4 * i;
        const ushort_t* bp = linT + (ct * 16 + lid) * 256 + quad * 8;
        M2[i] = (f32x4){0.f, 0.f, 0.f, 0.f};
#pragma unroll
        for (int ks = 0; ks < 8; ks++) {
            short8 bf = *(const short8*)&bp[ks * 32];
            M2[i] = __builtin_amdgcn_mfma_f32_16x16x32_bf16(af8[ks], bf, M2[i], 0, 0, 0);
        }
        float bias = LB[ct * 16 + lid];
#pragma unroll
        for (int reg = 0; reg < 4; reg++) M2[i][reg] += bias;
        int col = ct * 16 + lid, g = col >> 3, pos = col & 7;
#pragma unroll
        for (int reg = 0; reg < 4; reg++) {
            int rw = quad * 4 + reg;
            abuf[rw * 128 + ((g ^ (rw & 7)) * 8) + pos] = f2bf(M2[i][reg]);
        }
    }
    __syncthreads();
    // ---- T = gelu(m2 @ me_W0 + b0) ----
    short8 at[4];
#pragma unroll
    for (int kc = 0; kc < 4; kc++)
        at[kc] = *(const short8*)&abuf[lid * 128 + (((kc * 4 + quad) ^ (lid & 7)) * 8)];
#pragma unroll
    for (int i = 0; i < 2; i++) {
        int ct = wv + 4 * i;
        const ushort_t* bp = meT0 + (ct * 16 + lid) * 128 + quad * 8;
        f32x4 C = (f32x4){0.f, 0.f, 0.f, 0.f};
#pragma unroll
        for (int kc = 0; kc < 4; kc++) {
            short8 bf = *(const short8*)&bp[kc * 32];
            C = __builtin_amdgcn_mfma_f32_16x16x32_bf16(at[kc], bf, C, 0, 0, 0);
        }
        int col = ct * 16 + lid, g = col >> 3, pos = col & 7;
        float bias = B0[col];
#pragma unroll
        for (int reg = 0; reg < 4; reg++) {
            int rw = quad * 4 + reg;
            tbuf[rw * 128 + ((g ^ (rw & 7)) * 8) + pos] = f2bf(gelu_f(C[reg] + bias));
        }
    }
    __syncthreads();
    // ---- enc = T @ me_W1 + b1 ; R = m2 + enc ; ln2 ----
#pragma unroll
    for (int kc = 0; kc < 4; kc++)
        at[kc] = *(const short8*)&tbuf[lid * 128 + (((kc * 4 + quad) ^ (lid & 7)) * 8)];
    f32x4 R[2];
    float sr[4] = {0.f, 0.f, 0.f, 0.f}, ssr[4] = {0.f, 0.f, 0.f, 0.f};
#pragma unroll
    for (int i = 0; i < 2; i++) {
        int ct = wv + 4 * i;
        const ushort_t* bp = meT1 + (ct * 16 + lid) * 128 + quad * 8;
        f32x4 C = (f32x4){0.f, 0.f, 0.f, 0.f};
#pragma unroll
        for (int kc = 0; kc < 4; kc++) {
            short8 bf = *(const short8*)&bp[kc * 32];
            C = __builtin_amdgcn_mfma_f32_16x16x32_bf16(at[kc], bf, C, 0, 0, 0);
        }
        float bias = B1[ct * 16 + lid];
#pragma unroll
        for (int reg = 0; reg < 4; reg++) {
            float v = M2[i][reg] + C[reg] + bias;
            R[i][reg] = v;
            sr[reg] += v; ssr[reg] += v * v;
        }
    }
#pragma unroll
    for (int st = 1; st <= 8; st <<= 1)
#pragma unroll
        for (int reg = 0; reg < 4; reg++) {
            sr[reg] += __shfl_xor(sr[reg], st);
            ssr[reg] += __shfl_xor(ssr[reg], st);
        }
    if (lid == 0) {
#pragma unroll
        for (int reg = 0; reg < 4; reg++)
            red[wv * 16 + quad * 4 + reg] = make_float2(sr[reg], ssr[reg]);
    }
    __syncthreads();
    float mu2[4], rstd2[4];
#pragma unroll
    for (int reg = 0; reg < 4; reg++) {
        float S = 0.f, SS = 0.f;
#pragma unroll
        for (int w4 = 0; w4 < 4; w4++) {
            float2 p = red[w4 * 16 + quad * 4 + reg];
            S += p.x; SS += p.y;
        }
        mu2[reg] = S * (1.f / 128.f);
        float var = SS * (1.f / 128.f) - mu2[reg] * mu2[reg];
        rstd2[reg] = rsqrtf(var + 1e-5f);
    }
#pragma unroll
    for (int i = 0; i < 2; i++) {
        int col = (wv + 4 * i) * 16 + lid, g = col >> 3, pos = col & 7;
        float gv = g2[col], bv = b2[col];
#pragma unroll
        for (int reg = 0; reg < 4; reg++) {
            int rw = quad * 4 + reg;
            float v = (R[i][reg] - mu2[reg]) * rstd2[reg] * gv + bv;
            tbuf[rw * 128 + ((g ^ (rw & 7)) * 8) + pos] = f2bf(v);
        }
    }
    __syncthreads();
    // ---- V = gelu(r @ oh_W + ob) ; ln3 ; store ----
#pragma unroll
    for (int kc = 0; kc < 4; kc++)
        at[kc] = *(const short8*)&tbuf[lid * 128 + (((kc * 4 + quad) ^ (lid & 7)) * 8)];
    f32x4 V[2];
#pragma unroll
    for (int reg = 0; reg < 4; reg++) { sr[reg] = 0.f; ssr[reg] = 0.f; }
#pragma unroll
    for (int i = 0; i < 2; i++) {
        int ct = wv + 4 * i;
        const ushort_t* bp = ohT + (ct * 16 + lid) * 128 + quad * 8;
        f32x4 C = (f32x4){0.f, 0.f, 0.f, 0.f};
#pragma unroll
        for (int kc = 0; kc < 4; kc++) {
            short8 bf = *(const short8*)&bp[kc * 32];
            C = __builtin_amdgcn_mfma_f32_16x16x32_bf16(at[kc], bf, C, 0, 0, 0);
        }
        float bias = ob[ct * 16 + lid];
#pragma unroll
        for (int reg = 0; reg < 4; reg++) {
            float v = gelu_f(C[reg] + bias);
            V[i][reg] = v;
            sr[reg] += v; ssr[reg] += v * v;
        }
    }
#pragma unroll
    for (int st = 1; st <= 8; st <<= 1)
#pragma unroll
        for (int reg = 0; reg < 4; reg++) {
            sr[reg] += __shfl_xor(sr[reg], st);
            ssr[reg] += __shfl_xor(ssr[reg], st);
        }
    if (lid == 0) {
#pragma unroll
        for (int reg = 0; reg < 4; reg++)
            red[wv * 16 + quad * 4 + reg] = make_float2(sr[reg], ssr[reg]);
    }
    __syncthreads();
#pragma unroll
    for (int reg = 0; reg < 4; reg++) {
        float S = 0.f, SS = 0.f;
#pragma unroll
        for (int w4 = 0; w4 < 4; w4++) {
            float2 p = red[w4 * 16 + quad * 4 + reg];
            S += p.x; SS += p.y;
        }
        mu2[reg] = S * (1.f / 128.f);
        float var = SS * (1.f / 128.f) - mu2[reg] * mu2[reg];
        rstd2[reg] = rsqrtf(var + 1e-5f);
    }
#pragma unroll
    for (int i = 0; i < 2; i++) {
        int col = (wv + 4 * i) * 16 + lid;
        float gv = g3[col], bv = b3[col];
#pragma unroll
        for (int reg = 0; reg < 4; reg++)
            out[(b * 512 + n0 + quad * 4 + reg) * 128 + col] =
                (V[i][reg] - mu2[reg]) * rstd2[reg] * gv + bv;
    }
}

extern "C" void kernel_launch(void* const* d_in, const int* in_sizes, int n_in,
                              void* d_out, int out_size, void* d_ws, size_t ws_size,
                              hipStream_t stream) {
    const float* x      = (const float*)d_in[0];
    const int*   graph  = (const int*)d_in[1];
    const float* a_src0 = (const float*)d_in[3];
    const float* a_dst0 = (const float*)d_in[4];
    const float* a_src1 = (const float*)d_in[6];
    const float* a_dst1 = (const float*)d_in[7];
    float* out = (float*)d_out;

    float* ws  = (float*)d_ws;
    ushort_t* Ht0  = (ushort_t*)ws;               // 2097152 bf16
    ushort_t* Ht1  = Ht0 + 2097152;               // 2097152 bf16
    float*    e0s  = ws + 2097152;                // 65536
    float*    e0d  = e0s + 65536;                 // 65536
    float*    e1s  = e0d + 65536;                 // 16384
    float*    e1d  = e1s + 16384;                 // 16384
    ushort_t* WT   = (ushort_t*)(e1d + 16384);    // 114688 bf16
    ushort_t* linT = WT;                          // 32768
    ushort_t* meT0 = WT + 32768;                  // 16384
    ushort_t* meT1 = WT + 49152;                  // 16384
    ushort_t* ohT  = WT + 65536;                  // 16384
    ushort_t* W0T  = WT + 81920;                  // 16384
    ushort_t* W1T  = WT + 98304;                  // 16384
    unsigned* gmask = (unsigned*)(WT + 114688);   // 262144 uint32 = 1 MB

    prep_pack<<<1472, 256, 0, stream>>>((const float*)d_in[10], (const float*)d_in[12],
                                        (const float*)d_in[14], (const float*)d_in[18],
                                        (const float*)d_in[2], (const float*)d_in[5], WT,
                                        graph, gmask);
    gemm_mfma0<<<1024, 256, 0, stream>>>(x, W0T, Ht0, a_src0, a_dst0, e0s, e0d);
    gat0_gemm<<<dim3(32, 32), 256, 0, stream>>>(Ht0, e0s, e0d, gmask, W1T,
                                                a_src1, a_dst1, Ht1, e1s, e1d);
    gat1_head<<<dim3(32, 32), 256, 0, stream>>>(Ht1, e1s, e1d, gmask, x,
                                                (const float*)d_in[8], (const float*)d_in[9],
                                                linT, (const float*)d_in[11],
                                                meT0, (const float*)d_in[13],
                                                meT1, (const float*)d_in[15],
                                                (const float*)d_in[16], (const float*)d_in[17],
                                                ohT, (const float*)d_in[19],
                                                (const float*)d_in[20], (const float*)d_in[21],
                                                out);
}

// Round 7
// 181.654 us; speedup vs baseline: 1.0704x; 1.0023x over previous
//
#include <hip/hip_runtime.h>
#include <cmath>

// B=32, N=512, IN=128, HID=32, HEADS=4, OUT=128. fp32 in/out; graph int32.
// 4 dispatches: prep_w0 (tiny) ; gemm_fused (gemm_mfma0 ∥ pack_graph ∥ prep
// of remaining 5 weight transposes — no intra-dispatch deps) ; gat0_gemm ;
// gat1_head. gat0/gat1 are the measured-best R6 configs:
// gat0: BARRIER-FREE m-loop (per-lane P, head-indexed -> no duplicated exp),
//   per-wave dbuf linear global_load_lds of pre-swizzled Ht, counted vmcnt(4).
// gat1: shared-ps pipelined m-loop with DOUBLE-BUFFERED ps -> ONE s_barrier
//   per chunk (WAR on ps[t&1] has barrier t+1 between read@t and write@t+2).

typedef unsigned short ushort_t;
typedef __attribute__((ext_vector_type(8))) short short8;
typedef __attribute__((ext_vector_type(4))) short s16x4;
typedef __attribute__((ext_vector_type(4))) float f32x4;

__device__ __forceinline__ float gelu_f(float v) {
    return 0.5f * v * (1.0f + erff(v * 0.70710678118654752f));
}
__device__ __forceinline__ ushort_t f2bf(float x) {      // round-to-nearest-even
    union { float f; unsigned u; } v; v.f = x;
    return (ushort_t)((v.u + 0x7FFFu + ((v.u >> 16) & 1u)) >> 16);
}
__device__ __forceinline__ ushort_t f2bf_t(float x) {    // truncate (hot softmax path)
    union { float f; unsigned u; } v; v.f = x;
    return (ushort_t)(v.u >> 16);
}

// async 16B/lane global->LDS (LDS dest = wave-uniform base + lane*16)
__device__ __forceinline__ void gload_lds16(const ushort_t* g, ushort_t* l) {
    __builtin_amdgcn_global_load_lds((__attribute__((address_space(1))) void*)g,
                                     (__attribute__((address_space(3))) void*)l, 16, 0, 0);
}
// stage one 64-col chunk of pre-swizzled Ht: wave wv covers rows wv*32..+31.
__device__ __forceinline__ void stage_chunk(const ushort_t* src, ushort_t* dst,
                                            int wv, int lane) {
#pragma unroll
    for (int i = 0; i < 4; i++) {
        int rbase = wv * 32 + i * 8;
        gload_lds16(src + (rbase + (lane >> 3)) * 512 + (lane & 7) * 8,
                    dst + rbase * 64);
    }
}

// ---- D1: tiny — bf16-transpose W0 only (needed by gemm_fused) --------------
__global__ __launch_bounds__(256) void prep_w0(const float* __restrict__ W0,
                                               ushort_t* __restrict__ W0T) {
    int j = blockIdx.x * 256 + threadIdx.x;          // 16384 total
    int c = j >> 7, k = j & 127;
    W0T[j] = f2bf(W0[k * 128 + c]);
}

// ---- D2: gemm_mfma0 blocks ∥ pack_graph blocks ∥ prep-rest blocks ----------
__global__ __launch_bounds__(256) void gemm_fused(const float* __restrict__ X,
        const ushort_t* __restrict__ WTr, ushort_t* __restrict__ Ht,
        const float* __restrict__ a_s, const float* __restrict__ a_d,
        float* __restrict__ es, float* __restrict__ ed,
        const int* __restrict__ g, unsigned* __restrict__ gm,
        const float* __restrict__ lin_W, const float* __restrict__ me_W0,
        const float* __restrict__ me_W1, const float* __restrict__ oh_W,
        const float* __restrict__ W1, ushort_t* __restrict__ WT) {
    __shared__ __align__(16) ushort_t abuf[16 * 128];
    __shared__ __align__(16) ushort_t tb[128 * 24];
    __shared__ float2 ered[8 * 16];
    const int tid = threadIdx.x;
    if (blockIdx.x >= 1024) {
        if (blockIdx.x < 2048) {                     // pack_graph
            int idx = (blockIdx.x - 1024) * 256 + tid;   // 262144 = 32*512*16
            const int4* gp = (const int4*)g + (size_t)idx * 8;
            unsigned m = 0;
#pragma unroll
            for (int q = 0; q < 8; q++) {
                int4 v = gp[q];
                m |= (unsigned)(v.x > 0) << (q * 4 + 0);
                m |= (unsigned)(v.y > 0) << (q * 4 + 1);
                m |= (unsigned)(v.z > 0) << (q * 4 + 2);
                m |= (unsigned)(v.w > 0) << (q * 4 + 3);
            }
            gm[idx] = m;
        } else {                                     // prep other 5 weights
            int i = (blockIdx.x - 2048) * 256 + tid;     // 98304 total
            if (i < 32768)      { int c = i >> 8, k = i & 255;                   WT[i] = f2bf(lin_W[k * 128 + c]); }
            else if (i < 49152) { int j = i - 32768; int c = j >> 7, k = j & 127; WT[i] = f2bf(me_W0[k * 128 + c]); }
            else if (i < 65536) { int j = i - 49152; int c = j >> 7, k = j & 127; WT[i] = f2bf(me_W1[k * 128 + c]); }
            else if (i < 81920) { int j = i - 65536; int c = j >> 7, k = j & 127; WT[i] = f2bf(oh_W[k * 128 + c]); }
            else                { int j = i - 81920; int c = j >> 7, k = j & 127; WT[i + 16384] = f2bf(W1[k * 128 + c]); }
        }
        return;
    }
    // ---- gemm_mfma0 body: Ht bf16 = (X@W0)^T (PRE-SWIZZLED) + e_src/e_dst --
    const int row0 = blockIdx.x * 16;
    const int b = row0 >> 9, m0 = row0 & 511;
    const int w = tid >> 6, lane = tid & 63;
    const int quad = lane >> 4, lid = lane & 15;
    {
        int r = tid >> 4, g2 = tid & 15;
        const float4* src = (const float4*)(X + (row0 + r) * 128 + g2 * 8);
        float4 a = src[0], bb = src[1];
        short8 p;
        p[0] = (short)f2bf(a.x);  p[1] = (short)f2bf(a.y);
        p[2] = (short)f2bf(a.z);  p[3] = (short)f2bf(a.w);
        p[4] = (short)f2bf(bb.x); p[5] = (short)f2bf(bb.y);
        p[6] = (short)f2bf(bb.z); p[7] = (short)f2bf(bb.w);
        *(short8*)&abuf[r * 128 + ((g2 ^ (r & 7)) * 8)] = p;
    }
    __syncthreads();
    short8 af[4];
#pragma unroll
    for (int kc = 0; kc < 4; kc++)
        af[kc] = *(const short8*)&abuf[lid * 128 + (((kc * 4 + quad) ^ (lid & 7)) * 8)];
    f32x4 C[2];
#pragma unroll
    for (int i = 0; i < 2; i++) {
        int ct = w + 4 * i;
        const ushort_t* bp = WTr + (ct * 16 + lid) * 128 + quad * 8;
        C[i] = (f32x4){0.f, 0.f, 0.f, 0.f};
#pragma unroll
        for (int kc = 0; kc < 4; kc++) {
            short8 bf = *(const short8*)&bp[kc * 32];
            C[i] = __builtin_amdgcn_mfma_f32_16x16x32_bf16(af[kc], bf, C[i], 0, 0, 0);
        }
    }
#pragma unroll
    for (int i = 0; i < 2; i++) {
        int ct = w + 4 * i, col = ct * 16 + lid;
        float as_c = a_s[col], ad_c = a_d[col];
        float s0[4], d0[4];
#pragma unroll
        for (int r = 0; r < 4; r++) { s0[r] = C[i][r] * as_c; d0[r] = C[i][r] * ad_c; }
#pragma unroll
        for (int st = 1; st <= 8; st <<= 1)
#pragma unroll
            for (int r = 0; r < 4; r++) {
                s0[r] += __shfl_xor(s0[r], st);
                d0[r] += __shfl_xor(d0[r], st);
            }
        if (lid == 0) {
#pragma unroll
            for (int r = 0; r < 4; r++)
                ered[ct * 16 + quad * 4 + r] = make_float2(s0[r], d0[r]);
        }
#pragma unroll
        for (int r = 0; r < 4; r++)
            tb[col * 24 + quad * 4 + r] = f2bf(C[i][r]);
    }
    __syncthreads();
    if (tid < 64) {
        int row = tid & 15, h = tid >> 4;
        float2 pa = ered[(2 * h) * 16 + row], pb = ered[(2 * h + 1) * 16 + row];
        es[(b * 4 + h) * 512 + m0 + row] = pa.x + pb.x;
        ed[(b * 4 + h) * 512 + m0 + row] = pa.y + pb.y;
    }
    {   // pre-swizzled store: group g of m-chunk XORed with (c&7)
        int c = tid >> 1, half = tid & 1;
        int m = m0 + half * 8;
        int msw = (m & ~63) | ((((m >> 3) ^ c) & 7) << 3);
        *(short8*)&Ht[b * 65536 + c * 512 + msw] = *(const short8*)&tb[c * 24 + half * 8];
    }
}

// ---- K2: gat0 (barrier-free m-loop) -> elu -> gemm vs W1T -> Ht1, e1 -------
__global__ __launch_bounds__(256) void gat0_gemm(const ushort_t* __restrict__ Ht0,
        const float* __restrict__ es0, const float* __restrict__ ed0,
        const unsigned* __restrict__ gmask, const ushort_t* __restrict__ W1T,
        const float* __restrict__ a_s, const float* __restrict__ a_d,
        ushort_t* __restrict__ Ht1, float* __restrict__ es1, float* __restrict__ ed1) {
    __shared__ __align__(16) char smem[40960];
    ushort_t* hsb0 = (ushort_t*)smem;              // [0,16384) dbuf A
    ushort_t* hsb1 = (ushort_t*)(smem + 16384);    // [16384,32768) dbuf B
    float*    eds  = (float*)(smem + 32768);       // [32768,40960) e_dst 4 heads
    ushort_t* abuf = (ushort_t*)(smem + 32768);    // gemm phase (over eds), 4KB
    ushort_t* tb   = (ushort_t*)smem;              // gemm phase, 6KB
    float2*   ered = (float2*)(smem + 6144);       // gemm phase, 1KB
    const int tid = threadIdx.x;
    const int b = blockIdx.y, n0 = blockIdx.x * 16;
    const int wv = tid >> 6, lane = tid & 63;      // wv = head (gat) / col pair (gemm)
    const int quad = lane >> 4, lid = lane & 15;
    const int n = n0 + lid;                        // this lane's A-row (n-index)
    const ushort_t* hsrc = Ht0 + b * 65536;
    // per-lane P inputs: e_src scalar + 16 graph-mask words (64B)
    const float es_v = es0[b * 2048 + wv * 512 + n];
    const unsigned* gmrow = gmask + (b * 512 + n) * 16;
    uint4 gq0 = *(const uint4*)(gmrow);
    uint4 gq1 = *(const uint4*)(gmrow + 4);
    uint4 gq2 = *(const uint4*)(gmrow + 8);
    uint4 gq3 = *(const uint4*)(gmrow + 12);
    const unsigned mw[16] = {gq0.x, gq0.y, gq0.z, gq0.w, gq1.x, gq1.y, gq1.z, gq1.w,
                             gq2.x, gq2.y, gq2.z, gq2.w, gq3.x, gq3.y, gq3.z, gq3.w};
    {   // eds: all-heads e_dst (2048 floats) -> LDS, read-only in the loop
        const float4* src = (const float4*)(ed0 + b * 2048);
        float4 v0 = src[tid * 2], v1 = src[tid * 2 + 1];
        ((float4*)eds)[tid * 2] = v0;
        ((float4*)eds)[tid * 2 + 1] = v1;
    }
    __builtin_amdgcn_sched_barrier(0);
    stage_chunk(hsrc, hsb0, wv, lane);             // prologue: chunk 0 in flight
    __builtin_amdgcn_sched_barrier(0);
    asm volatile("s_waitcnt lgkmcnt(0)" ::: "memory");
    __builtin_amdgcn_s_barrier();                  // eds visible; chunk0 still in flight
    __builtin_amdgcn_sched_barrier(0);
    const short8 onesf = {0x3F80, 0x3F80, 0x3F80, 0x3F80, 0x3F80, 0x3F80, 0x3F80, 0x3F80};
    f32x4 acc[2], dsf;
    acc[0] = (f32x4){0.f, 0.f, 0.f, 0.f};
    acc[1] = (f32x4){0.f, 0.f, 0.f, 0.f};
    dsf = (f32x4){0.f, 0.f, 0.f, 0.f};
#pragma unroll
    for (int t = 0; t < 8; t++) {
        ushort_t* cbuf = (t & 1) ? hsb1 : hsb0;
        // ---- per-lane A-fragment P (head wv, row n, m = t*64+kc*32+quad*8) ----
        short8 af[2];
#pragma unroll
        for (int kc = 0; kc < 2; kc++) {
            const int base = t * 64 + kc * 32 + quad * 8;
            unsigned mb8 = (mw[2 * t + kc] >> (quad * 8)) & 0xffu;
            if ((unsigned)(n - base) < 8u) mb8 |= 1u << (n - base);   // self-loop
            float4 e0v = *(const float4*)&eds[wv * 512 + base];
            float4 e1v = *(const float4*)&eds[wv * 512 + base + 4];
            float ev[8] = {e0v.x, e0v.y, e0v.z, e0v.w, e1v.x, e1v.y, e1v.z, e1v.w};
            short8 pk;
#pragma unroll
            for (int j = 0; j < 8; j++) {
                float e = es_v + ev[j];
                e = fmaxf(e, 0.2f * e);
                e = ((mb8 >> j) & 1u) ? e : -1e30f;
                pk[j] = (short)f2bf_t(__expf(e));
            }
            af[kc] = pk;
        }
        if (t < 7) stage_chunk(hsrc + (t + 1) * 64, (t & 1) ? hsb0 : hsb1, wv, lane);
        __builtin_amdgcn_sched_barrier(0);          // pin stage above the wait
        if (t < 7) asm volatile("s_waitcnt vmcnt(4)" ::: "memory");   // own chunk t done
        else       asm volatile("s_waitcnt vmcnt(0)" ::: "memory");
        __builtin_amdgcn_sched_barrier(0);          // pin ds_reads below the wait
#pragma unroll
        for (int kc = 0; kc < 2; kc++) {
            const int gsw = ((kc * 4 + quad) ^ (lid & 7)) * 8;
            short8 b0 = *(const short8*)&cbuf[(wv * 32 + lid) * 64 + gsw];
            short8 b1 = *(const short8*)&cbuf[(wv * 32 + 16 + lid) * 64 + gsw];
            acc[0] = __builtin_amdgcn_mfma_f32_16x16x32_bf16(af[kc], b0, acc[0], 0, 0, 0);
            acc[1] = __builtin_amdgcn_mfma_f32_16x16x32_bf16(af[kc], b1, acc[1], 0, 0, 0);
            dsf = __builtin_amdgcn_mfma_f32_16x16x32_bf16(af[kc], onesf, dsf, 0, 0, 0);
        }
    }
    __syncthreads();                                // gat LDS dead; overlays safe
    // ---- m = elu(softmax-agg) -> bf16 A-tile ----
#pragma unroll
    for (int reg = 0; reg < 4; reg++) {
        float inv = 1.0f / dsf[reg];
        int rw = quad * 4 + reg;
#pragma unroll
        for (int ch = 0; ch < 2; ch++) {
            float v = acc[ch][reg] * inv;
            v = v > 0.f ? v : expm1f(v);            // ELU
            int col = wv * 32 + ch * 16 + lid;
            abuf[rw * 128 + (((col >> 3) ^ (rw & 7)) * 8) + (col & 7)] = f2bf(v);
        }
    }
    __syncthreads();
    // ---- gemm vs W1T + fused e1 (1 head) + Ht1 ----
    short8 af[4];
#pragma unroll
    for (int kc = 0; kc < 4; kc++)
        af[kc] = *(const short8*)&abuf[lid * 128 + (((kc * 4 + quad) ^ (lid & 7)) * 8)];
    f32x4 C[2];
#pragma unroll
    for (int i = 0; i < 2; i++) {
        int ct = wv + 4 * i;
        const ushort_t* bp = W1T + (ct * 16 + lid) * 128 + quad * 8;
        C[i] = (f32x4){0.f, 0.f, 0.f, 0.f};
#pragma unroll
        for (int kc = 0; kc < 4; kc++) {
            short8 bf = *(const short8*)&bp[kc * 32];
            C[i] = __builtin_amdgcn_mfma_f32_16x16x32_bf16(af[kc], bf, C[i], 0, 0, 0);
        }
    }
#pragma unroll
    for (int i = 0; i < 2; i++) {
        int ct = wv + 4 * i, col = ct * 16 + lid;
        float as_c = a_s[col], ad_c = a_d[col];
        float s0[4], d0[4];
#pragma unroll
        for (int r = 0; r < 4; r++) { s0[r] = C[i][r] * as_c; d0[r] = C[i][r] * ad_c; }
#pragma unroll
        for (int st = 1; st <= 8; st <<= 1)
#pragma unroll
            for (int r = 0; r < 4; r++) {
                s0[r] += __shfl_xor(s0[r], st);
                d0[r] += __shfl_xor(d0[r], st);
            }
        if (lid == 0) {
#pragma unroll
            for (int r = 0; r < 4; r++)
                ered[ct * 16 + quad * 4 + r] = make_float2(s0[r], d0[r]);
        }
#pragma unroll
        for (int r = 0; r < 4; r++)
            tb[col * 24 + quad * 4 + r] = f2bf(C[i][r]);
    }
    __syncthreads();
    if (tid < 16) {
        float S = 0.f, D = 0.f;
#pragma unroll
        for (int ct = 0; ct < 8; ct++) { float2 p = ered[ct * 16 + tid]; S += p.x; D += p.y; }
        es1[b * 512 + n0 + tid] = S;
        ed1[b * 512 + n0 + tid] = D;
    }
    {   // pre-swizzled store for gat1's linear global_load_lds staging
        int c = tid >> 1, half = tid & 1;
        int m = n0 + half * 8;
        int msw = (m & ~63) | ((((m >> 3) ^ c) & 7) << 3);
        *(short8*)&Ht1[b * 65536 + c * 512 + msw] = *(const short8*)&tb[c * 24 + half * 8];
    }
}

// ---- K3: gat1 (shared-ps, ONE barrier/chunk) -> ln1 -> linear -> MLP -> ... -
__global__ __launch_bounds__(256) void gat1_head(const ushort_t* __restrict__ Ht,
        const float* __restrict__ es1, const float* __restrict__ ed1,
        const unsigned* __restrict__ gmask, const float* __restrict__ x,
        const float* __restrict__ g1, const float* __restrict__ b1,
        const ushort_t* __restrict__ linT, const float* __restrict__ LB,
        const ushort_t* __restrict__ meT0, const float* __restrict__ B0,
        const ushort_t* __restrict__ meT1, const float* __restrict__ B1,
        const float* __restrict__ g2, const float* __restrict__ b2,
        const ushort_t* __restrict__ ohT, const float* __restrict__ ob,
        const float* __restrict__ g3, const float* __restrict__ b3,
        float* __restrict__ out) {
    __shared__ __align__(16) char smem[38912];
    ushort_t* hsb0 = (ushort_t*)smem;              // [0,16384) dbuf A
    ushort_t* hsb1 = (ushort_t*)(smem + 16384);    // [16384,32768) dbuf B
    ushort_t* ps0  = (ushort_t*)(smem + 32768);    // [32768,34816) P dbuf A
    ushort_t* ps1  = (ushort_t*)(smem + 34816);    // [34816,36864) P dbuf B
    float*    eds  = (float*)(smem + 36864);       // [36864,38912) e_dst row
    ushort_t* ybuf = (ushort_t*)smem;              // head phase overlays
    ushort_t* abuf = (ushort_t*)(smem + 8192);
    ushort_t* tbuf = (ushort_t*)(smem + 12288);
    float*    gbuf = (float*)(smem + 16384);
    float2*   red  = (float2*)(smem + 24832);
    float2*   mvs  = (float2*)(smem + 25344);
    const int tid = threadIdx.x;
    const int b = blockIdx.y, n0 = blockIdx.x * 16;
    const int wv = tid >> 6, lane = tid & 63;
    const int quad = lane >> 4, lid = lane & 15;
    const int pn = tid >> 4, q = tid & 15, off = q * 4;   // P: 256 thr x 4 m
    const int ng = n0 + pn;
    const ushort_t* hsrc = Ht + b * 65536;
    const float es_v = es1[b * 512 + ng];
    const unsigned* gmrow = gmask + (b * 512 + ng) * 16;
    unsigned mword[8];
#pragma unroll
    for (int t = 0; t < 8; t++) mword[t] = gmrow[2 * t + (q >> 3)];
    float2 edv = ((const float2*)(ed1 + b * 512))[tid];
    stage_chunk(hsrc, hsb0, wv, lane);             // prologue: chunk 0 in flight
    ((float2*)eds)[tid] = edv;
    asm volatile("s_waitcnt lgkmcnt(0)" ::: "memory");
    __builtin_amdgcn_s_barrier();                  // eds visible; chunk0 still in flight
    __builtin_amdgcn_sched_barrier(0);
    const short8 onesf = {0x3F80, 0x3F80, 0x3F80, 0x3F80, 0x3F80, 0x3F80, 0x3F80, 0x3F80};
    f32x4 acc[2], dsf;
    acc[0] = (f32x4){0.f, 0.f, 0.f, 0.f};
    acc[1] = (f32x4){0.f, 0.f, 0.f, 0.f};
    dsf = (f32x4){0.f, 0.f, 0.f, 0.f};
#pragma unroll
    for (int t = 0; t < 8; t++) {
        const int mc = t * 64;
        ushort_t* cbuf = (t & 1) ? hsb1 : hsb0;
        ushort_t* pbuf = (t & 1) ? ps1 : ps0;
        const int mbase = mc + off;
        float4 ev4 = *(const float4*)&eds[mbase];
        if (t < 7) stage_chunk(hsrc + mc + 64, (t & 1) ? hsb0 : hsb1, wv, lane);
        unsigned mb4 = (mword[t] >> ((q & 7) * 4)) & 0xFu;
        if ((unsigned)(ng - mbase) < 4u) mb4 |= 1u << (ng - mbase);   // self-loop
        float ev[4] = {ev4.x, ev4.y, ev4.z, ev4.w};
        s16x4 pk;
#pragma unroll
        for (int j = 0; j < 4; j++) {
            float e = es_v + ev[j];
            e = fmaxf(e, 0.2f * e);
            e = ((mb4 >> j) & 1u) ? e : -1e30f;
            pk[j] = (short)f2bf_t(__expf(e));
        }
        *(s16x4*)&pbuf[pn * 64 + (((off >> 3) ^ (pn & 7)) * 8) + (off & 7)] = pk;
        if (t < 7) asm volatile("s_waitcnt vmcnt(4)" ::: "memory");
        else       asm volatile("s_waitcnt vmcnt(0)" ::: "memory");
        asm volatile("s_waitcnt lgkmcnt(0)" ::: "memory");
        __builtin_amdgcn_s_barrier();               // single barrier per chunk
        __builtin_amdgcn_sched_barrier(0);          // pin LDS reads below the waits
#pragma unroll
        for (int kc = 0; kc < 2; kc++) {
            const int gsw = ((kc * 4 + quad) ^ (lid & 7)) * 8;
            short8 a = *(const short8*)&pbuf[lid * 64 + gsw];
            short8 b0 = *(const short8*)&cbuf[(wv * 32 + lid) * 64 + gsw];
            short8 b1 = *(const short8*)&cbuf[(wv * 32 + 16 + lid) * 64 + gsw];
            acc[0] = __builtin_amdgcn_mfma_f32_16x16x32_bf16(a, b0, acc[0], 0, 0, 0);
            acc[1] = __builtin_amdgcn_mfma_f32_16x16x32_bf16(a, b1, acc[1], 0, 0, 0);
            dsf = __builtin_amdgcn_mfma_f32_16x16x32_bf16(a, onesf, dsf, 0, 0, 0);
        }
    }
    __syncthreads();                                // gat LDS dead; overlays safe
#pragma unroll
    for (int reg = 0; reg < 4; reg++) {
        float inv = 1.0f / dsf[reg];
        int rw = quad * 4 + reg;
#pragma unroll
        for (int ch = 0; ch < 2; ch++)
            gbuf[rw * 132 + wv * 32 + ch * 16 + lid] = acc[ch][reg] * inv;
    }
    __syncthreads();
    // ---- LN1 over concat(x,G); ybuf bf16 ----
    const int r = tid >> 4, c16 = tid & 15;
    const float4* xp = (const float4*)(x + (b * 512 + n0 + r) * 128);
    float4 vv4[4];
    float s = 0.f, ss = 0.f;
#pragma unroll
    for (int i = 0; i < 4; i++) {
        int c4 = c16 * 4 + i;
        float4 v = (c4 < 32) ? xp[c4] : *(const float4*)&gbuf[r * 132 + (c4 - 32) * 4];
        vv4[i] = v;
        s += v.x + v.y + v.z + v.w;
        ss += v.x * v.x + v.y * v.y + v.z * v.z + v.w * v.w;
    }
#pragma unroll
    for (int st = 1; st <= 8; st <<= 1) { s += __shfl_xor(s, st); ss += __shfl_xor(ss, st); }
    if (c16 == 0) {
        float mu = s * (1.f / 256.f);
        float var = ss * (1.f / 256.f) - mu * mu;
        mvs[r] = make_float2(mu, rsqrtf(var + 1e-5f));
    }
    __syncthreads();
    {
        float mu = mvs[r].x, rstd = mvs[r].y;
#pragma unroll
        for (int half = 0; half < 2; half++) {
            int g = c16 * 2 + half, c0 = g * 8;
            float va[8] = {vv4[half * 2].x, vv4[half * 2].y, vv4[half * 2].z, vv4[half * 2].w,
                           vv4[half * 2 + 1].x, vv4[half * 2 + 1].y, vv4[half * 2 + 1].z, vv4[half * 2 + 1].w};
            short8 p;
#pragma unroll
            for (int e = 0; e < 8; e++)
                p[e] = (short)f2bf((va[e] - mu) * rstd * g1[c0 + e] + b1[c0 + e]);
            *(short8*)&ybuf[r * 256 + ((g ^ (r & 7)) * 8)] = p;
        }
    }
    __syncthreads();
    // ---- GEMM1: M2 = y @ lin_W + lin_b ----
    short8 af8[8];
#pragma unroll
    for (int ks = 0; ks < 8; ks++)
        af8[ks] = *(const short8*)&ybuf[lid * 256 + (((ks * 4 + quad) ^ (lid & 7)) * 8)];
    f32x4 M2[2];
#pragma unroll
    for (int i = 0; i < 2; i++) {
        int ct = wv + 4 * i;
        const ushort_t* bp = linT + (ct * 16 + lid) * 256 + quad * 8;
        M2[i] = (f32x4){0.f, 0.f, 0.f, 0.f};
#pragma unroll
        for (int ks = 0; ks < 8; ks++) {
            short8 bf = *(const short8*)&bp[ks * 32];
            M2[i] = __builtin_amdgcn_mfma_f32_16x16x32_bf16(af8[ks], bf, M2[i], 0, 0, 0);
        }
        float bias = LB[ct * 16 + lid];
#pragma unroll
        for (int reg = 0; reg < 4; reg++) M2[i][reg] += bias;
        int col = ct * 16 + lid, g = col >> 3, pos = col & 7;
#pragma unroll
        for (int reg = 0; reg < 4; reg++) {
            int rw = quad * 4 + reg;
            abuf[rw * 128 + ((g ^ (rw & 7)) * 8) + pos] = f2bf(M2[i][reg]);
        }
    }
    __syncthreads();
    // ---- T = gelu(m2 @ me_W0 + b0) ----
    short8 at[4];
#pragma unroll
    for (int kc = 0; kc < 4; kc++)
        at[kc] = *(const short8*)&abuf[lid * 128 + (((kc * 4 + quad) ^ (lid & 7)) * 8)];
#pragma unroll
    for (int i = 0; i < 2; i++) {
        int ct = wv + 4 * i;
        const ushort_t* bp = meT0 + (ct * 16 + lid) * 128 + quad * 8;
        f32x4 C = (f32x4){0.f, 0.f, 0.f, 0.f};
#pragma unroll
        for (int kc = 0; kc < 4; kc++) {
            short8 bf = *(const short8*)&bp[kc * 32];
            C = __builtin_amdgcn_mfma_f32_16x16x32_bf16(at[kc], bf, C, 0, 0, 0);
        }
        int col = ct * 16 + lid, g = col >> 3, pos = col & 7;
        float bias = B0[col];
#pragma unroll
        for (int reg = 0; reg < 4; reg++) {
            int rw = quad * 4 + reg;
            tbuf[rw * 128 + ((g ^ (rw & 7)) * 8) + pos] = f2bf(gelu_f(C[reg] + bias));
        }
    }
    __syncthreads();
    // ---- enc = T @ me_W1 + b1 ; R = m2 + enc ; ln2 ----
#pragma unroll
    for (int kc = 0; kc < 4; kc++)
        at[kc] = *(const short8*)&tbuf[lid * 128 + (((kc * 4 + quad) ^ (lid & 7)) * 8)];
    f32x4 R[2];
    float sr[4] = {0.f, 0.f, 0.f, 0.f}, ssr[4] = {0.f, 0.f, 0.f, 0.f};
#pragma unroll
    for (int i = 0; i < 2; i++) {
        int ct = wv + 4 * i;
        const ushort_t* bp = meT1 + (ct * 16 + lid) * 128 + quad * 8;
        f32x4 C = (f32x4){0.f, 0.f, 0.f, 0.f};
#pragma unroll
        for (int kc = 0; kc < 4; kc++) {
            short8 bf = *(const short8*)&bp[kc * 32];
            C = __builtin_amdgcn_mfma_f32_16x16x32_bf16(at[kc], bf, C, 0, 0, 0);
        }
        float bias = B1[ct * 16 + lid];
#pragma unroll
        for (int reg = 0; reg < 4; reg++) {
            float v = M2[i][reg] + C[reg] + bias;
            R[i][reg] = v;
            sr[reg] += v; ssr[reg] += v * v;
        }
    }
#pragma unroll
    for (int st = 1; st <= 8; st <<= 1)
#pragma unroll
        for (int reg = 0; reg < 4; reg++) {
            sr[reg] += __shfl_xor(sr[reg], st);
            ssr[reg] += __shfl_xor(ssr[reg], st);
        }
    if (lid == 0) {
#pragma unroll
        for (int reg = 0; reg < 4; reg++)
            red[wv * 16 + quad * 4 + reg] = make_float2(sr[reg], ssr[reg]);
    }
    __syncthreads();
    float mu2[4], rstd2[4];
#pragma unroll
    for (int reg = 0; reg < 4; reg++) {
        float S = 0.f, SS = 0.f;
#pragma unroll
        for (int w4 = 0; w4 < 4; w4++) {
            float2 p = red[w4 * 16 + quad * 4 + reg];
            S += p.x; SS += p.y;
        }
        mu2[reg] = S * (1.f / 128.f);
        float var = SS * (1.f / 128.f) - mu2[reg] * mu2[reg];
        rstd2[reg] = rsqrtf(var + 1e-5f);
    }
#pragma unroll
    for (int i = 0; i < 2; i++) {
        int col = (wv + 4 * i) * 16 + lid, g = col >> 3, pos = col & 7;
        float gv = g2[col], bv = b2[col];
#pragma unroll
        for (int reg = 0; reg < 4; reg++) {
            int rw = quad * 4 + reg;
            float v = (R[i][reg] - mu2[reg]) * rstd2[reg] * gv + bv;
            tbuf[rw * 128 + ((g ^ (rw & 7)) * 8) + pos] = f2bf(v);
        }
    }
    __syncthreads();
    // ---- V = gelu(r @ oh_W + ob) ; ln3 ; store ----
#pragma unroll
    for (int kc = 0; kc < 4; kc++)
        at[kc] = *(const short8*)&tbuf[lid * 128 + (((kc * 4 + quad) ^ (lid & 7)) * 8)];
    f32x4 V[2];
#pragma unroll
    for (int reg = 0; reg < 4; reg++) { sr[reg] = 0.f; ssr[reg] = 0.f; }
#pragma unroll
    for (int i = 0; i < 2; i++) {
        int ct = wv + 4 * i;
        const ushort_t* bp = ohT + (ct * 16 + lid) * 128 + quad * 8;
        f32x4 C = (f32x4){0.f, 0.f, 0.f, 0.f};
#pragma unroll
        for (int kc = 0; kc < 4; kc++) {
            short8 bf = *(const short8*)&bp[kc * 32];
            C = __builtin_amdgcn_mfma_f32_16x16x32_bf16(at[kc], bf, C, 0, 0, 0);
        }
        float bias = ob[ct * 16 + lid];
#pragma unroll
        for (int reg = 0; reg < 4; reg++) {
            float v = gelu_f(C[reg] + bias);
            V[i][reg] = v;
            sr[reg] += v; ssr[reg] += v * v;
        }
    }
#pragma unroll
    for (int st = 1; st <= 8; st <<= 1)
#pragma unroll
        for (int reg = 0; reg < 4; reg++) {
            sr[reg] += __shfl_xor(sr[reg], st);
            ssr[reg] += __shfl_xor(ssr[reg], st);
        }
    if (lid == 0) {
#pragma unroll
        for (int reg = 0; reg < 4; reg++)
            red[wv * 16 + quad * 4 + reg] = make_float2(sr[reg], ssr[reg]);
    }
    __syncthreads();
#pragma unroll
    for (int reg = 0; reg < 4; reg++) {
        float S = 0.f, SS = 0.f;
#pragma unroll
        for (int w4 = 0; w4 < 4; w4++) {
            float2 p = red[w4 * 16 + quad * 4 + reg];
            S += p.x; SS += p.y;
        }
        mu2[reg] = S * (1.f / 128.f);
        float var = SS * (1.f / 128.f) - mu2[reg] * mu2[reg];
        rstd2[reg] = rsqrtf(var + 1e-5f);
    }
#pragma unroll
    for (int i = 0; i < 2; i++) {
        int col = (wv + 4 * i) * 16 + lid;
        float gv = g3[col], bv = b3[col];
#pragma unroll
        for (int reg = 0; reg < 4; reg++)
            out[(b * 512 + n0 + quad * 4 + reg) * 128 + col] =
                (V[i][reg] - mu2[reg]) * rstd2[reg] * gv + bv;
    }
}

extern "C" void kernel_launch(void* const* d_in, const int* in_sizes, int n_in,
                              void* d_out, int out_size, void* d_ws, size_t ws_size,
                              hipStream_t stream) {
    const float* x      = (const float*)d_in[0];
    const int*   graph  = (const int*)d_in[1];
    const float* a_src0 = (const float*)d_in[3];
    const float* a_dst0 = (const float*)d_in[4];
    const float* a_src1 = (const float*)d_in[6];
    const float* a_dst1 = (const float*)d_in[7];
    float* out = (float*)d_out;

    float* ws  = (float*)d_ws;
    ushort_t* Ht0  = (ushort_t*)ws;               // 2097152 bf16
    ushort_t* Ht1  = Ht0 + 2097152;               // 2097152 bf16
    float*    e0s  = ws + 2097152;                // 65536
    float*    e0d  = e0s + 65536;                 // 65536
    float*    e1s  = e0d + 65536;                 // 16384
    float*    e1d  = e1s + 16384;                 // 16384
    ushort_t* WT   = (ushort_t*)(e1d + 16384);    // 114688 bf16
    ushort_t* linT = WT;                          // 32768
    ushort_t* meT0 = WT + 32768;                  // 16384
    ushort_t* meT1 = WT + 49152;                  // 16384
    ushort_t* ohT  = WT + 65536;                  // 16384
    ushort_t* W0T  = WT + 81920;                  // 16384
    ushort_t* W1T  = WT + 98304;                  // 16384
    unsigned* gmask = (unsigned*)(WT + 114688);   // 262144 uint32 = 1 MB

    prep_w0<<<64, 256, 0, stream>>>((const float*)d_in[2], W0T);
    gemm_fused<<<2432, 256, 0, stream>>>(x, W0T, Ht0, a_src0, a_dst0, e0s, e0d,
                                         graph, gmask,
                                         (const float*)d_in[10], (const float*)d_in[12],
                                         (const float*)d_in[14], (const float*)d_in[18],
                                         (const float*)d_in[5], WT);
    gat0_gemm<<<dim3(32, 32), 256, 0, stream>>>(Ht0, e0s, e0d, gmask, W1T,
                                                a_src1, a_dst1, Ht1, e1s, e1d);
    gat1_head<<<dim3(32, 32), 256, 0, stream>>>(Ht1, e1s, e1d, gmask, x,
                                                (const float*)d_in[8], (const float*)d_in[9],
                                                linT, (const float*)d_in[11],
                                                meT0, (const float*)d_in[13],
                                                meT1, (const float*)d_in[15],
                                                (const float*)d_in[16], (const float*)d_in[17],
                                                ohT, (const float*)d_in[19],
                                                (const float*)d_in[20], (const float*)d_in[21],
                                                out);
}